// Round 7
// baseline (222.964 us; speedup 1.0000x reference)
//
#include <hip/hip_runtime.h>
#include <math.h>

#define H_ 8
#define B_ 8
#define N_ 1024
#define D_ 64
#define DIMM 512
#define NROWS 8192

typedef __attribute__((ext_vector_type(8))) short s8v;
typedef __attribute__((ext_vector_type(4))) float f4v;
typedef __attribute__((ext_vector_type(2))) unsigned int u2v;
union fragu { s8v v; unsigned int w[4]; uint4 q; };

#define BMFMA(a, b, c) __builtin_amdgcn_mfma_f32_16x16x32_bf16(a, b, c, 0, 0, 0)

__device__ __forceinline__ float wred_sum(float v) {
#pragma unroll
    for (int m = 32; m >= 1; m >>= 1) v += __shfl_xor(v, m, 64);
    return v;
}
__device__ __forceinline__ double wred_sum_d(double v) {
#pragma unroll
    for (int m = 32; m >= 1; m >>= 1) v += __shfl_xor(v, m, 64);
    return v;
}
// packed RN bf16 convert: low16 = bf16(a), high16 = bf16(b)
__device__ __forceinline__ unsigned cvtpk(float a, float b) {
    unsigned r;
    asm("v_cvt_pk_bf16_f32 %0, %1, %2" : "=v"(r) : "v"(a), "v"(b));
    return r;
}
// RN split: a ~= hi + lo (both RN bf16)
__device__ __forceinline__ void bsplit(float a, unsigned short& hi, unsigned short& lo) {
    unsigned h = cvtpk(a, 0.f);
    hi = (unsigned short)h;
    float r = a - __uint_as_float(h << 16);
    lo = (unsigned short)cvtpk(r, 0.f);
}
// split 8 f32 -> 4 packed u32 RN-hi pairs + 4 packed u32 RN-lo pairs
__device__ __forceinline__ void split8(const float* a, unsigned* hw, unsigned* lw) {
#pragma unroll
    for (int i = 0; i < 4; ++i) {
        unsigned h = cvtpk(a[2 * i], a[2 * i + 1]);
        hw[i] = h;
        float l0 = a[2 * i]     - __uint_as_float(h << 16);
        float l1 = a[2 * i + 1] - __uint_as_float(h & 0xFFFF0000u);
        lw[i] = cvtpk(l0, l1);
    }
}

// fast 2^x (v_exp_f32 IS 2^x)
__device__ __forceinline__ float fexp2(float x) {
#if __has_builtin(__builtin_amdgcn_exp2f)
    return __builtin_amdgcn_exp2f(x);
#else
    return exp2f(x);
#endif
}

#if __has_builtin(__builtin_amdgcn_permlane16_swap) && __has_builtin(__builtin_amdgcn_permlane32_swap)
#define HAVE_PLSWAP 1
#endif

// max over the 4 lanes {l, l^16, l^32, l^48} — VALU-only (no DS pipe)
__device__ __forceinline__ float kbmax4(float x) {
#ifdef HAVE_PLSWAP
    u2v a = __builtin_amdgcn_permlane16_swap(__float_as_uint(x), __float_as_uint(x), false, false);
    float m = fmaxf(__uint_as_float(a[0]), __uint_as_float(a[1]));
    u2v c = __builtin_amdgcn_permlane32_swap(__float_as_uint(m), __float_as_uint(m), false, false);
    return fmaxf(__uint_as_float(c[0]), __uint_as_float(c[1]));
#else
    x = fmaxf(x, __shfl_xor(x, 16, 64));
    return fmaxf(x, __shfl_xor(x, 32, 64));
#endif
}
// sum over the 4 lanes {l, l^16, l^32, l^48} — VALU-only
__device__ __forceinline__ float kbsum4(float x) {
#ifdef HAVE_PLSWAP
    u2v a = __builtin_amdgcn_permlane16_swap(__float_as_uint(x), __float_as_uint(x), false, false);
    float m = __uint_as_float(a[0]) + __uint_as_float(a[1]);
    u2v c = __builtin_amdgcn_permlane32_swap(__float_as_uint(m), __float_as_uint(m), false, false);
    return __uint_as_float(c[0]) + __uint_as_float(c[1]);
#else
    x += __shfl_xor(x, 16, 64);
    x += __shfl_xor(x, 32, 64);
    return x;
#endif
}

// ---------------- K0: fused LN stats (q,k,v) + g-scaled W transpose/split + c1/c2 ----------------
// LN folded into W: Wthi/Wtlo hold (g ∘ W_in)^T split; c1_j = Σ g_k W_kj, c2_j = Σ b_k W_kj.
__global__ __launch_bounds__(256) void k_prep(
    const float* __restrict__ q, const float* __restrict__ k, const float* __restrict__ v,
    float* __restrict__ muv, float* __restrict__ rsd,
    const float* __restrict__ Win, const float* __restrict__ Wout,
    unsigned short* __restrict__ Wthi, unsigned short* __restrict__ Wtlo,
    unsigned short* __restrict__ Wothi, unsigned short* __restrict__ Wotlo,
    const float* __restrict__ lng, const float* __restrict__ lnb,
    float* __restrict__ c1, float* __restrict__ c2)
{
    int bx = blockIdx.x;
    __shared__ float S[64][65];
    __shared__ float r1[4][64], r2[4][64];
    int t = threadIdx.x;
    if (bx < 6144) {
        int w = t >> 6, lane = t & 63;
        int row = bx * 4 + w;
        int tens = row >> 13;
        int lrow = row & 8191;
        const float* src = (tens == 0) ? q : (tens == 1 ? k : v);
        const float* p = src + (long long)lrow * DIMM + lane * 8;
        float4 a = *(const float4*)p;
        float4 b = *(const float4*)(p + 4);
        float s  = a.x + a.y + a.z + a.w + b.x + b.y + b.z + b.w;
        float sq = a.x*a.x + a.y*a.y + a.z*a.z + a.w*a.w + b.x*b.x + b.y*b.y + b.z*b.z + b.w*b.w;
        s = wred_sum(s); sq = wred_sum(sq);
        if (lane == 0) {
            float m = s * (1.f / 512.f);
            float var = sq * (1.f / 512.f) - m * m;
            muv[row] = m;
            rsd[row] = rsqrtf(var + 1e-5f);
        }
        return;
    }
    if (bx >= 6272) {
        // c1/c2 blocks: 8 blocks x 64 columns
        int cb = bx - 6272;
        int j0c = cb * 64;
        int jj = t & 63, chunk = t >> 6;
        float s1 = 0.f, s2 = 0.f;
        for (int kk = chunk * 128; kk < chunk * 128 + 128; ++kk) {
            float wv = Win[(long long)kk * DIMM + j0c + jj];
            s1 = fmaf(lng[kk], wv, s1);
            s2 = fmaf(lnb[kk], wv, s2);
        }
        r1[chunk][jj] = s1;
        r2[chunk][jj] = s2;
        __syncthreads();
        if (t < 64) {
            c1[j0c + t] = r1[0][t] + r1[1][t] + r1[2][t] + r1[3][t];
            c2[j0c + t] = r2[0][t] + r2[1][t] + r2[2][t] + r2[3][t];
        }
        return;
    }
    int sb = bx - 6144;          // 0..127: [z][jx][kx]
    int z = sb >> 6;
    int rem = sb & 63;
    int kxi = rem & 7, jxi = rem >> 3;
    const float* Wsrc = z ? Wout : Win;
    unsigned short* Dhi = z ? Wothi : Wthi;
    unsigned short* Dlo = z ? Wotlo : Wtlo;
    int k0 = kxi * 64, j0 = jxi * 64;
    int rr = t >> 2, seg = t & 3;
    const float* p = Wsrc + (long long)(k0 + rr) * DIMM + j0 + seg * 16;
    float4 a0 = *(const float4*)p, a1 = *(const float4*)(p + 4),
           a2 = *(const float4*)(p + 8), a3 = *(const float4*)(p + 12);
    if (z == 0) {
        float gval = lng[k0 + rr];   // fold LN gamma into W_in
        a0.x*=gval; a0.y*=gval; a0.z*=gval; a0.w*=gval;
        a1.x*=gval; a1.y*=gval; a1.z*=gval; a1.w*=gval;
        a2.x*=gval; a2.y*=gval; a2.z*=gval; a2.w*=gval;
        a3.x*=gval; a3.y*=gval; a3.z*=gval; a3.w*=gval;
    }
    S[rr][seg*16+ 0]=a0.x; S[rr][seg*16+ 1]=a0.y; S[rr][seg*16+ 2]=a0.z; S[rr][seg*16+ 3]=a0.w;
    S[rr][seg*16+ 4]=a1.x; S[rr][seg*16+ 5]=a1.y; S[rr][seg*16+ 6]=a1.z; S[rr][seg*16+ 7]=a1.w;
    S[rr][seg*16+ 8]=a2.x; S[rr][seg*16+ 9]=a2.y; S[rr][seg*16+10]=a2.z; S[rr][seg*16+11]=a2.w;
    S[rr][seg*16+12]=a3.x; S[rr][seg*16+13]=a3.y; S[rr][seg*16+14]=a3.z; S[rr][seg*16+15]=a3.w;
    __syncthreads();
    float f[16];
#pragma unroll
    for (int i = 0; i < 16; ++i) f[i] = S[seg * 16 + i][rr];
    unsigned hw[8], lw[8];
    split8(f, hw, lw);
    split8(f + 8, hw + 4, lw + 4);
    long long ob = (long long)(j0 + rr) * DIMM + k0 + seg * 16;
    *(uint4*)&Dhi[ob]     = make_uint4(hw[0], hw[1], hw[2], hw[3]);
    *(uint4*)&Dhi[ob + 8] = make_uint4(hw[4], hw[5], hw[6], hw[7]);
    *(uint4*)&Dlo[ob]     = make_uint4(lw[0], lw[1], lw[2], lw[3]);
    *(uint4*)&Dlo[ob + 8] = make_uint4(lw[4], lw[5], lw[6], lw[7]);
}

// ---------------- K1: input projection with LN folded out of the hot loop ----------------
// Main loop: plain GEMM of RAW x against (g∘W)^T split. Epilogue applies
// acc = rs*acc + (-rs*mu*c1_j + c2_j) before the (unchanged) stats/store code.
__global__ __launch_bounds__(256) void k_gemm_in(
    const float* __restrict__ qx, const float* __restrict__ kx, const float* __restrict__ vx,
    const float* __restrict__ muv, const float* __restrict__ rsd,
    const float* __restrict__ c1, const float* __restrict__ c2,
    const unsigned short* __restrict__ Wthi, const unsigned short* __restrict__ Wtlo,
    unsigned short* __restrict__ Fqhi, unsigned short* __restrict__ Fqlo,
    unsigned short* __restrict__ Fkhi, unsigned short* __restrict__ Fklo,
    unsigned short* __restrict__ Fvthi, unsigned short* __restrict__ Fvtlo,
    float* __restrict__ qinv, float* __restrict__ mq,
    float* __restrict__ kinv, float* __restrict__ ks,
    float* __restrict__ csq, float* __restrict__ csk)
{
    int tens = blockIdx.z;
    const float* X = (tens == 0) ? qx : (tens == 1 ? kx : vx);
    int row0 = blockIdx.x * 128, hq = blockIdx.y;
    const float* muT = muv + tens * NROWS;
    const float* rsT = rsd + tens * NROWS;
    __shared__ unsigned short Ah[128][32], Al[128][32];
    __shared__ unsigned short Bh[128][32], Bl[128][32];
    int t = threadIdx.x;
    int w = t >> 6, lane = t & 63, l15 = lane & 15, kb = lane >> 4;
    int srow = t >> 1, sseg = t & 1;
    int sw = (srow >> 1) & 3;
    int c0 = ((2 * sseg + 0) ^ sw) * 8;
    int c1c = ((2 * sseg + 1) ^ sw) * 8;
    int rs = (l15 >> 1) & 3;
    int rb = (kb ^ rs) * 8;
    f4v acc[2][8];
#pragma unroll
    for (int rt = 0; rt < 2; ++rt)
#pragma unroll
        for (int dt = 0; dt < 8; ++dt) acc[rt][dt] = (f4v){0.f, 0.f, 0.f, 0.f};

    float4 x0, x1, x2, x3;
    uint4 wh0, wh1, wl0, wl1;
#define GIN_LOAD(KC) { \
    int kO = (KC) * 32 + sseg * 16; \
    const float* xp = X + (long long)(row0 + srow) * DIMM + kO; \
    x0 = *(const float4*)xp;       x1 = *(const float4*)(xp + 4); \
    x2 = *(const float4*)(xp + 8); x3 = *(const float4*)(xp + 12); \
    const unsigned short* wph = Wthi + (long long)(hq * 128 + srow) * DIMM + kO; \
    const unsigned short* wpl = Wtlo + (long long)(hq * 128 + srow) * DIMM + kO; \
    wh0 = *(const uint4*)wph; wh1 = *(const uint4*)(wph + 8); \
    wl0 = *(const uint4*)wpl; wl1 = *(const uint4*)(wpl + 8); }

    GIN_LOAD(0)
    for (int kc = 0; kc < 16; ++kc) {
        float av[16];
        av[ 0]=x0.x; av[ 1]=x0.y; av[ 2]=x0.z; av[ 3]=x0.w;
        av[ 4]=x1.x; av[ 5]=x1.y; av[ 6]=x1.z; av[ 7]=x1.w;
        av[ 8]=x2.x; av[ 9]=x2.y; av[10]=x2.z; av[11]=x2.w;
        av[12]=x3.x; av[13]=x3.y; av[14]=x3.z; av[15]=x3.w;
        unsigned hw[8], lw[8];
        split8(av, hw, lw);
        split8(av + 8, hw + 4, lw + 4);
        *(uint4*)&Ah[srow][c0]  = make_uint4(hw[0], hw[1], hw[2], hw[3]);
        *(uint4*)&Ah[srow][c1c] = make_uint4(hw[4], hw[5], hw[6], hw[7]);
        *(uint4*)&Al[srow][c0]  = make_uint4(lw[0], lw[1], lw[2], lw[3]);
        *(uint4*)&Al[srow][c1c] = make_uint4(lw[4], lw[5], lw[6], lw[7]);
        *(uint4*)&Bh[srow][c0]  = wh0;
        *(uint4*)&Bh[srow][c1c] = wh1;
        *(uint4*)&Bl[srow][c0]  = wl0;
        *(uint4*)&Bl[srow][c1c] = wl1;
        __syncthreads();
        if (kc < 15) { GIN_LOAD(kc + 1) }   // overlap next-tile loads with MFMA
        fragu ah[2], al2[2];
#pragma unroll
        for (int rt = 0; rt < 2; ++rt) {
            ah[rt].v  = *(const s8v*)&Ah[w * 32 + rt * 16 + l15][rb];
            al2[rt].v = *(const s8v*)&Al[w * 32 + rt * 16 + l15][rb];
        }
#pragma unroll
        for (int dt = 0; dt < 8; ++dt) {
            s8v bh = *(const s8v*)&Bh[dt * 16 + l15][rb];
            s8v bl = *(const s8v*)&Bl[dt * 16 + l15][rb];
#pragma unroll
            for (int rt = 0; rt < 2; ++rt) {
                acc[rt][dt] = BMFMA(ah[rt].v, bh, acc[rt][dt]);
                acc[rt][dt] = BMFMA(ah[rt].v, bl, acc[rt][dt]);
                acc[rt][dt] = BMFMA(al2[rt].v, bh, acc[rt][dt]);
            }
        }
        __syncthreads();
    }
#undef GIN_LOAD
    // ---- LN epilogue: acc = rs*acc + (-rs*mu*c1_j + c2_j) ----
    {
        float rs_rr[2][4], rmu_rr[2][4];
#pragma unroll
        for (int rt = 0; rt < 2; ++rt)
#pragma unroll
            for (int r = 0; r < 4; ++r) {
                int rw = row0 + w * 32 + rt * 16 + kb * 4 + r;
                float rv = rsT[rw];
                rs_rr[rt][r]  = rv;
                rmu_rr[rt][r] = rv * muT[rw];
            }
#pragma unroll
        for (int dt = 0; dt < 8; ++dt) {
            int j = (hq * 2 + (dt >> 2)) * 64 + (dt & 3) * 16 + l15;
            float c1v = c1[j], c2v = c2[j];
#pragma unroll
            for (int rt = 0; rt < 2; ++rt)
#pragma unroll
                for (int r = 0; r < 4; ++r)
                    acc[rt][dt][r] = fmaf(rs_rr[rt][r], acc[rt][dt][r],
                                          fmaf(-rmu_rr[rt][r], c1v, c2v));
        }
    }
    int b = row0 >> 10;
    if (tens < 2) {
        unsigned short* Dh = tens ? Fkhi : Fqhi;
        unsigned short* Dl = tens ? Fklo : Fqlo;
#pragma unroll
        for (int rt = 0; rt < 2; ++rt) {
            int nloc = (row0 & 1023) + w * 32 + rt * 16 + kb * 4;
#pragma unroll
            for (int dt = 0; dt < 8; ++dt) {
                int hb = (hq * 2 + (dt >> 2)) * 8 + b;
#pragma unroll
                for (int r = 0; r < 4; ++r) {
                    unsigned short hi, lo;
                    bsplit(acc[rt][dt][r], hi, lo);
                    long long idx = ((long long)hb * N_ + nloc + r) * D_ + (dt & 3) * 16 + l15;
                    Dh[idx] = hi;
                    Dl[idx] = lo;
                }
            }
#pragma unroll
            for (int hh = 0; hh < 2; ++hh) {
                int hb2 = (hq * 2 + hh) * 8 + b;
#pragma unroll
                for (int r = 0; r < 4; ++r) {
                    float a0 = acc[rt][hh*4+0][r], a1 = acc[rt][hh*4+1][r],
                          a2 = acc[rt][hh*4+2][r], a3 = acc[rt][hh*4+3][r];
                    float s  = a0 + a1 + a2 + a3;
                    float sq = a0*a0 + a1*a1 + a2*a2 + a3*a3;
#pragma unroll
                    for (int msk = 8; msk >= 1; msk >>= 1) {
                        s  += __shfl_xor(s, msk, 64);
                        sq += __shfl_xor(sq, msk, 64);
                    }
                    if (l15 == 0) {
                        int rowg = hb2 * N_ + nloc + r;
                        float inv = 1.f / (sqrtf(sq) + 1e-6f);
                        if (tens) { kinv[rowg] = inv; ks[rowg] = s; }
                        else      { qinv[rowg] = inv; mq[rowg] = s * (1.f / 64.f); }
                    }
                }
            }
        }
        float* cs = tens ? csk : csq;
#pragma unroll
        for (int dt = 0; dt < 8; ++dt) {
            int hb2 = (hq * 2 + (dt >> 2)) * 8 + b;
            float c = acc[0][dt][0] + acc[0][dt][1] + acc[0][dt][2] + acc[0][dt][3]
                    + acc[1][dt][0] + acc[1][dt][1] + acc[1][dt][2] + acc[1][dt][3];
            c += __shfl_xor(c, 16, 64);
            c += __shfl_xor(c, 32, 64);
            if (kb == 0) atomicAdd(&cs[hb2 * 64 + (dt & 3) * 16 + l15], c);
        }
    } else {
        // V^T store, phi-permuted within each 64-key tile:
        // in-tile row bits [w&1][rt][kb][r] -> pos [w&1][kb][rt][r]
#pragma unroll
        for (int dt = 0; dt < 8; ++dt) {
            int hb = (hq * 2 + (dt >> 2)) * 8 + b;
#pragma unroll
            for (int rt = 0; rt < 2; ++rt) {
                int vcol = (row0 & 1023) + (w >> 1) * 64 + (w & 1) * 32 + (kb << 3) + (rt << 2);
                unsigned short hh4[4], ll4[4];
#pragma unroll
                for (int r = 0; r < 4; ++r) bsplit(acc[rt][dt][r], hh4[r], ll4[r]);
                long long idx = ((long long)hb * D_ + (dt & 3) * 16 + l15) * N_ + vcol;
                *(uint2*)&Fvthi[idx] = make_uint2((unsigned)hh4[0] | ((unsigned)hh4[1] << 16),
                                                  (unsigned)hh4[2] | ((unsigned)hh4[3] << 16));
                *(uint2*)&Fvtlo[idx] = make_uint2((unsigned)ll4[0] | ((unsigned)ll4[1] << 16),
                                                  (unsigned)ll4[2] | ((unsigned)ll4[3] << 16));
            }
        }
    }
}

// ---------------- K2: fused g-vector + weight-predictor MLP (one launch) ----------------
__global__ __launch_bounds__(512) void k_gvec_mlp(
    const unsigned short* __restrict__ Fqhi, const unsigned short* __restrict__ Fqlo,
    const float* __restrict__ csk, const float* __restrict__ mq, float* __restrict__ g,
    const float* __restrict__ csq,
    const float* __restrict__ W1, const float* __restrict__ b1,
    const float* __restrict__ lg, const float* __restrict__ lb,
    const float* __restrict__ W2, const float* __restrict__ b2,
    const float* __restrict__ W3, const float* __restrict__ b3,
    const float* __restrict__ wtemp, float* __restrict__ wbuf)
{
    int bx = blockIdx.x;
    int t = threadIdx.x;
    if (bx < 128) {
        __shared__ float mk[64];
        __shared__ float smkv;
        int hb = bx >> 1;
        int r0 = (bx & 1) * 512;
        if (t < 64) mk[t] = csk[hb * 64 + t] * (1.f / 1024.f);
        __syncthreads();
        if (t == 0) {
            float s = 0;
            for (int i = 0; i < 64; ++i) s += mk[i];
            smkv = s;
        }
        __syncthreads();
        float smk = smkv;
        int rowg = hb * N_ + r0 + t;
        const uint4* ph = (const uint4*)(Fqhi + (long long)rowg * D_);
        const uint4* pl = (const uint4*)(Fqlo + (long long)rowg * D_);
        float acc = 0.f;
#pragma unroll
        for (int i = 0; i < 8; ++i) {
            uint4 hh = ph[i];
            uint4 ll = pl[i];
            const unsigned* hu = &hh.x;
            const unsigned* lu = &ll.x;
#pragma unroll
            for (int j = 0; j < 4; ++j) {
                float v0 = __uint_as_float((hu[j] & 0xFFFFu) << 16) + __uint_as_float((lu[j] & 0xFFFFu) << 16);
                float v1 = __uint_as_float(hu[j] & 0xFFFF0000u) + __uint_as_float(lu[j] & 0xFFFF0000u);
                acc = fmaf(v0, mk[i * 8 + j * 2], acc);
                acc = fmaf(v1, mk[i * 8 + j * 2 + 1], acc);
            }
        }
        g[rowg] = acc - mq[rowg] * smk;
        return;
    }
    // ---- MLP (one block, 512 threads) ----
    __shared__ float cat[8][128];
    __shared__ float z1[8][64];
    __shared__ float zr[8][64];
    __shared__ float z2[8][32];
    __shared__ float z3[8][3];
    __shared__ float lnmu[8], lnrs[8];
    {
        int h = t >> 6, dd = t & 63;
        float sq = 0, sk = 0;
        for (int b = 0; b < 8; ++b) {
            sq += csq[(h * 8 + b) * 64 + dd];
            sk += csk[(h * 8 + b) * 64 + dd];
        }
        cat[h][dd]      = sq * (1.f / 8192.f);
        cat[h][64 + dd] = sk * (1.f / 8192.f);
    }
    __syncthreads();
    {
        int h = t >> 6, j = t & 63;
        float a = b1[j];
        for (int i = 0; i < 128; ++i) a = fmaf(cat[h][i], W1[i * 64 + j], a);
        z1[h][j] = a;
    }
    __syncthreads();
    if (t < 8) {
        float m = 0;
        for (int j = 0; j < 64; ++j) m += z1[t][j];
        m *= (1.f / 64.f);
        float v2 = 0;
        for (int j = 0; j < 64; ++j) { float d = z1[t][j] - m; v2 += d * d; }
        v2 *= (1.f / 64.f);
        lnmu[t] = m; lnrs[t] = rsqrtf(v2 + 1e-5f);
    }
    __syncthreads();
    {
        int h = t >> 6, j = t & 63;
        float z = (z1[h][j] - lnmu[h]) * lnrs[h] * lg[j] + lb[j];
        zr[h][j] = fmaxf(z, 0.f);
    }
    __syncthreads();
    if (t < 256) {
        int h = t >> 5, j2 = t & 31;
        float a = b2[j2];
        for (int j = 0; j < 64; ++j) a = fmaf(zr[h][j], W2[j * 32 + j2], a);
        z2[h][j2] = fmaxf(a, 0.f);
    }
    __syncthreads();
    if (t < 24) {
        int h = t / 3, c = t % 3;
        float a = b3[c];
        for (int j2 = 0; j2 < 32; ++j2) a = fmaf(z2[h][j2], W3[j2 * 3 + c], a);
        z3[h][c] = a;
    }
    __syncthreads();
    if (t < 8) {
        int h = t;
        float wt = fminf(fmaxf(wtemp[0], 0.1f), 10.f);
        float a = z3[h][0], b = z3[h][1], c = z3[h][2];
        float mx = fmaxf(a, fmaxf(b, c));
        float ea = expf(a - mx), eb = expf(b - mx), ec = expf(c - mx);
        float s = ea + eb + ec;
        float p0 = ea / s, p1 = eb / s, p2 = ec / s;
        float q0 = p0 / wt, q1 = p1 / wt, q2 = p2 / wt;
        mx = fmaxf(q0, fmaxf(q1, q2));
        ea = expf(q0 - mx); eb = expf(q1 - mx); ec = expf(q2 - mx);
        s = ea + eb + ec;
        wbuf[h * 3 + 0] = (ea / s) * 0.7f + 0.1f;
        wbuf[h * 3 + 1] = (eb / s) * 0.7f + 0.1f;
        wbuf[h * 3 + 2] = (ec / s) * 0.7f + 0.1f;
    }
}

// ---------------- K4: pass 1 — single RN-bf16 MFMA (stats only), 4-way key split ----------------
__global__ __launch_bounds__(256) void k_pass1(
    const unsigned short* __restrict__ Fqhi, const unsigned short* __restrict__ Fkhi,
    const float* __restrict__ qinvA, const float* __restrict__ mqA, const float* __restrict__ gA,
    const float* __restrict__ kinvA, const float* __restrict__ ksA,
    float* __restrict__ rowA, float* __restrict__ rowM,
    double* __restrict__ accum)
{
    int bx = blockIdx.x;
    int loc = bx >> 3;
    int hb = (bx & 7) * 8 + (loc >> 6);
    int rem = loc & 63;
    int n0 = (rem >> 2) * 64;
    int mtc = rem & 3;
    int h = hb >> 3;
    __shared__ unsigned short Khi[64][72];
    __shared__ float ki1s[64], ksls[64];
    __shared__ double wsum[4][4];
    int t = threadIdx.x;
    int w = t >> 6, lane = t & 63, l15 = lane & 15, kb = lane >> 4;
    int srow = t >> 2, seg = t & 3;
    const float SC = (float)((0.001 / 1024.0) / (8.0 + 1e-6));

    fragu qh[2];
    {
        long long qbase = ((long long)hb * N_ + n0 + w * 16 + l15) * D_;
#pragma unroll
        for (int k2 = 0; k2 < 2; ++k2)
            qh[k2].q = *(const uint4*)(Fqhi + qbase + k2 * 32 + kb * 8);
    }
    float qi1_r[4], qm_r[4], qgs_r[4];
#pragma unroll
    for (int r = 0; r < 4; ++r) {
        int rowg = hb * N_ + n0 + w * 16 + kb * 4 + r;
        qi1_r[r] = qinvA[rowg];
        qm_r[r]  = mqA[rowg];
        qgs_r[r] = gA[rowg] * SC;
    }
    // sacc: 0=SumA 1=SumA2 2=SumB2 3=SumAB 4=Sum min(A,0.01)
    float sacc[5][4] = {};

    for (int mt = mtc * 4; mt < mtc * 4 + 4; ++mt) {
        {
            long long kro = ((long long)hb * N_ + mt * 64 + srow) * D_ + seg * 16;
            uint4 h0 = *(const uint4*)(Fkhi + kro), h1 = *(const uint4*)(Fkhi + kro + 8);
            *(uint4*)&Khi[srow][seg * 16]     = h0;
            *(uint4*)&Khi[srow][seg * 16 + 8] = h1;
            if (t < 64) {
                ki1s[t] = kinvA[hb * N_ + mt * 64 + t];
                ksls[t] = ksA[hb * N_ + mt * 64 + t];
            }
        }
        __syncthreads();
#pragma unroll
        for (int nt = 0; nt < 4; ++nt) {
            f4v acc = {0.f, 0.f, 0.f, 0.f};
            s8v kh0 = *(const s8v*)&Khi[nt * 16 + l15][kb * 8];
            s8v kh1 = *(const s8v*)&Khi[nt * 16 + l15][32 + kb * 8];
            acc = BMFMA(qh[0].v, kh0, acc);
            acc = BMFMA(qh[1].v, kh1, acc);
            int key = nt * 16 + l15;
            float k1 = ki1s[key];
            float ksvSC = ksls[key] * SC;
            float e_r[4];
#pragma unroll
            for (int r = 0; r < 4; ++r) e_r[r] = fmaf(qm_r[r], ksvSC, qgs_r[r]);
#pragma unroll
            for (int r = 0; r < 4; ++r) {
                float dv = acc[r];
                float A  = dv * qi1_r[r] * k1;
                float Bv = fmaf(dv, SC, -e_r[r]);
                sacc[0][r] += A;
                sacc[1][r] = fmaf(A, A, sacc[1][r]);
                sacc[2][r] = fmaf(Bv, Bv, sacc[2][r]);
                sacc[3][r] = fmaf(A, Bv, sacc[3][r]);
                sacc[4][r] += fminf(A, 0.01f);
            }
        }
        __syncthreads();
    }
    {
        const int map[4] = {0, 3, 4, 6};
#pragma unroll
        for (int qq = 0; qq < 4; ++qq) {
            float s = sacc[qq][0] + sacc[qq][1] + sacc[qq][2] + sacc[qq][3];
            double d = wred_sum_d((double)s);
            if (lane == 0) wsum[qq][w] = d;
        }
        __syncthreads();
        if (t < 4) {
            double tot = wsum[t][0] + wsum[t][1] + wsum[t][2] + wsum[t][3];
            atomicAdd(&accum[h * 9 + map[t]], tot);
        }
    }
    float vA[4], vM[4];
#pragma unroll
    for (int r = 0; r < 4; ++r) {
        float a = sacc[0][r], m = sacc[4][r];
#pragma unroll
        for (int msk = 8; msk >= 1; msk >>= 1) {
            a += __shfl_xor(a, msk, 64);
            m += __shfl_xor(m, msk, 64);
        }
        vA[r] = a; vM[r] = m;
    }
    if (l15 == 0) {
#pragma unroll
        for (int r = 0; r < 4; ++r) {
            int rowg = hb * N_ + n0 + w * 16 + kb * 4 + r;
            atomicAdd(&rowA[rowg], vA[r]);
            // Σ max(0.01-A,0) over this block's 256 keys = 0.01*256 - Σ min(A,0.01)
            atomicAdd(&rowM[rowg], 2.56f - vM[r]);
        }
    }
}

// ---------------- K4b: row-sum finalization + varC + (last block) global finalize ----------------
__global__ __launch_bounds__(256) void k_rowfin(
    const float* __restrict__ rowA, const float* __restrict__ rowM,
    float* __restrict__ varC, double* __restrict__ accum,
    const float* __restrict__ wbuf, float* __restrict__ scl,
    unsigned* __restrict__ ticket)
{
    int hb = blockIdx.x;
    int h = hb >> 3;
    int t = threadIdx.x;
    int w = t >> 6, lane = t & 63;
    __shared__ double wsum[3][4];
    double c2 = 0, c5 = 0, c7 = 0;
    for (int i = t; i < N_; i += 256) {
        int idx = hb * N_ + i;
        float rm = rowM[idx];
        float C = rm * (1.f / 1024.f);
        varC[idx] = C;
        c2 += (double)rm;
        c5 += (double)rm * (double)C;
        c7 += (double)C * (double)rowA[idx];
    }
    c2 = wred_sum_d(c2); c5 = wred_sum_d(c5); c7 = wred_sum_d(c7);
    if (lane == 0) { wsum[0][w] = c2; wsum[1][w] = c5; wsum[2][w] = c7; }
    __syncthreads();
    if (t < 3) {
        const int map[3] = {2, 5, 7};
        double tot = wsum[t][0] + wsum[t][1] + wsum[t][2] + wsum[t][3];
        atomicAdd(&accum[h * 9 + map[t]], tot);
    }
    // ---- last block to finish runs the (tiny) global finalize ----
    __syncthreads();   // drains the t<3 atomics (waitcnt before barrier)
    __shared__ unsigned lastv;
    if (t == 0) {
        __threadfence();
        lastv = atomicAdd(ticket, 1u);
    }
    __syncthreads();
    if (lastv != 63 || t != 0) return;

    double av[8][9];
#pragma unroll
    for (int hh = 0; hh < 8; ++hh)
#pragma unroll
        for (int j = 0; j < 9; ++j)
            av[hh][j] = __hip_atomic_load(&accum[hh * 9 + j], __ATOMIC_RELAXED, __HIP_MEMORY_SCOPE_AGENT);
    const double T = 67108864.0;
    double GA = 0, GB = 0, GC = 0, GAA = 0, GBB = 0, GCC = 0;
#pragma unroll
    for (int hh = 0; hh < 8; ++hh) {
        GA += av[hh][0]; GB += av[hh][1]; GC += av[hh][2];
        GAA += av[hh][3]; GBB += av[hh][4]; GCC += av[hh][5];
    }
    double cos_n = sqrt(fmax((GAA - GA * GA / T) / (T - 1.0), 0.0)) + 1e-6;
    double cov_n = sqrt(fmax((GBB - GB * GB / T) / (T - 1.0), 0.0)) + 1e-6;
    double var_n = sqrt(fmax((GCC - GC * GC / T) / (T - 1.0), 0.0)) + 1e-6;
    double sd = 0, sd2 = 0;
    double al[8], be[8], ga[8];
#pragma unroll
    for (int hh = 0; hh < 8; ++hh) {
        al[hh] = (double)wbuf[hh * 3 + 0] / cos_n;
        be[hh] = (double)wbuf[hh * 3 + 1] * 0.3 / cov_n;
        ga[hh] = (double)wbuf[hh * 3 + 2] * 0.3 / var_n;
        sd  += al[hh] * av[hh][0] + be[hh] * av[hh][1] + ga[hh] * av[hh][2];
        sd2 += al[hh] * al[hh] * av[hh][3] + be[hh] * be[hh] * av[hh][4] + ga[hh] * ga[hh] * av[hh][5]
             + 2.0 * al[hh] * be[hh] * av[hh][6] + 2.0 * al[hh] * ga[hh] * av[hh][7]
             + 2.0 * be[hh] * ga[hh] * av[hh][8];
    }
    double vard = fmax((sd2 - sd * sd / T) / (T - 1.0), 0.0);
    double temp = 0.5 + sqrt(vard);
    temp = fmin(fmax(temp, 0.3), 3.0);
#pragma unroll
    for (int hh = 0; hh < 8; ++hh) {
        scl[hh * 3 + 0] = (float)(al[hh] / temp);
        scl[hh * 3 + 1] = (float)(be[hh] / temp);
        scl[hh * 3 + 2] = (float)(ga[hh] / temp);
    }
}

// ---------------- K5: pass 2 — 8 waves x 32 q-rows/wave, 256 rows/block ----------------
__global__ __launch_bounds__(512, 2) void k_pass2(
    const unsigned short* __restrict__ Fqhi, const unsigned short* __restrict__ Fqlo,
    const unsigned short* __restrict__ Fkhi, const unsigned short* __restrict__ Fklo,
    const unsigned short* __restrict__ Fvthi, const unsigned short* __restrict__ Fvtlo,
    const float* __restrict__ qinvA, const float* __restrict__ mqA, const float* __restrict__ gA,
    const float* __restrict__ kinvA, const float* __restrict__ ksA,
    const float* __restrict__ varC, const float* __restrict__ scl,
    unsigned short* __restrict__ attn_hi, unsigned short* __restrict__ attn_lo)
{
    int bx = blockIdx.x;
    int g = bx >> 3;
    int hb = (bx & 7) * 8 + (g >> 2);   // XCD-local hb
    int n0 = (g & 3) * 256;             // 256 q-rows per block
    int h = hb >> 3, b = hb & 7;
    __shared__ unsigned short Khi[2][64][72];
    __shared__ unsigned short Klo[2][64][72];
    __shared__ unsigned short Vh[2][64][72];
    __shared__ unsigned short Vl[2][64][72];
    __shared__ float ki1s[2][64], ksls[2][64];
    int t = threadIdx.x;
    int w = t >> 6, lane = t & 63, l15 = lane & 15, kb = lane >> 4;
    int srow = t >> 3, sc = (t & 7) * 8;
    const float SC = (float)((0.001 / 1024.0) / (8.0 + 1e-6));
    const float L2E = 1.44269504f;      // log2(e): work in exp2 domain
    float sAh = scl[h*3+0] * L2E, sBh = scl[h*3+1] * L2E, sCh = scl[h*3+2] * L2E;
    float SCb = SC * sBh;

    fragu qh0[2], ql0[2], qh1[2], ql1[2];
    int rowq0 = hb * N_ + n0 + w * 32 + l15;
    int rowq1 = rowq0 + 16;
    {
        long long qb0 = (long long)rowq0 * D_;
        long long qb1 = (long long)rowq1 * D_;
#pragma unroll
        for (int k2 = 0; k2 < 2; ++k2) {
            qh0[k2].q = *(const uint4*)(Fqhi + qb0 + k2 * 32 + kb * 8);
            ql0[k2].q = *(const uint4*)(Fqlo + qb0 + k2 * 32 + kb * 8);
            qh1[k2].q = *(const uint4*)(Fqhi + qb1 + k2 * 32 + kb * 8);
            ql1[k2].q = *(const uint4*)(Fqlo + qb1 + k2 * 32 + kb * 8);
        }
    }
    float qiA0 = qinvA[rowq0] * sAh;
    float qiA1 = qinvA[rowq1] * sAh;
    float nqmS0 = -mqA[rowq0] * SCb;
    float nqmS1 = -mqA[rowq1] * SCb;
    float cb0 = fmaf(sCh, varC[rowq0], -(gA[rowq0] * SC) * sBh);
    float cb1 = fmaf(sCh, varC[rowq1], -(gA[rowq1] * SC) * sBh);

    float Mr0 = -1e30f, Lr0 = 0.f, Mr1 = -1e30f, Lr1 = 0.f;
    f4v oacc0[4], oacc1[4];
#pragma unroll
    for (int dt = 0; dt < 4; ++dt) {
        oacc0[dt] = (f4v){0.f, 0.f, 0.f, 0.f};
        oacc1[dt] = (f4v){0.f, 0.f, 0.f, 0.f};
    }
    int idxr[4];
#pragma unroll
    for (int r = 0; r < 4; ++r) idxr[r] = (kb * 20 + r) * 4;

    uint4 rkh, rkl, rvh, rvl;
    float rki, rks;
#define P2_LOAD(MT) { \
    long long kro = ((long long)hb * N_ + (MT) * 64 + srow) * D_ + sc; \
    rkh = *(const uint4*)(Fkhi + kro); rkl = *(const uint4*)(Fklo + kro); \
    long long vro = ((long long)hb * D_ + srow) * N_ + (MT) * 64 + sc; \
    rvh = *(const uint4*)(Fvthi + vro); rvl = *(const uint4*)(Fvtlo + vro); \
    if (t < 64) { rki = kinvA[hb * N_ + (MT) * 64 + t]; rks = ksA[hb * N_ + (MT) * 64 + t]; } }

    P2_LOAD(0)
    for (int mt = 0; mt < 16; ++mt) {
        int buf = mt & 1;
        *(uint4*)&Khi[buf][srow][sc] = rkh;
        *(uint4*)&Klo[buf][srow][sc] = rkl;
        *(uint4*)&Vh[buf][srow][sc]  = rvh;
        *(uint4*)&Vl[buf][srow][sc]  = rvl;
        if (t < 64) { ki1s[buf][t] = rki; ksls[buf][t] = rks; }
        __syncthreads();
        if (mt < 15) { P2_LOAD(mt + 1) }
        float p0[4][4], p1[4][4];
#pragma unroll
        for (int nt = 0; nt < 4; ++nt) {
            f4v a0 = {0.f, 0.f, 0.f, 0.f};
            f4v a1 = {0.f, 0.f, 0.f, 0.f};
            __builtin_amdgcn_s_setprio(1);
#pragma unroll
            for (int k2 = 0; k2 < 2; ++k2) {
                s8v kh = *(const s8v*)&Khi[buf][nt * 16 + l15][k2 * 32 + kb * 8];
                s8v kl = *(const s8v*)&Klo[buf][nt * 16 + l15][k2 * 32 + kb * 8];
                a0 = BMFMA(kh, qh0[k2].v, a0);
                a0 = BMFMA(kh, ql0[k2].v, a0);
                a0 = BMFMA(kl, qh0[k2].v, a0);
                a1 = BMFMA(kh, qh1[k2].v, a1);
                a1 = BMFMA(kh, ql1[k2].v, a1);
                a1 = BMFMA(kl, qh1[k2].v, a1);
            }
            __builtin_amdgcn_s_setprio(0);
            float4 k1v = *(const float4*)&ki1s[buf][nt * 16 + kb * 4];
            float4 ksv = *(const float4*)&ksls[buf][nt * 16 + kb * 4];
            float k1a[4] = {k1v.x, k1v.y, k1v.z, k1v.w};
            float ksa[4] = {ksv.x, ksv.y, ksv.z, ksv.w};
#pragma unroll
            for (int r = 0; r < 4; ++r) {
                p0[nt][r] = fmaf(a0[r], fmaf(qiA0, k1a[r], SCb), fmaf(nqmS0, ksa[r], cb0));
                p1[nt][r] = fmaf(a1[r], fmaf(qiA1, k1a[r], SCb), fmaf(nqmS1, ksa[r], cb1));
            }
        }
        fragu pah0[2], pal0[2], pah1[2], pal1[2];
        // ---- softmax row-group 0 ----
        {
            float tmax = fmaxf(fmaxf(fmaxf(p0[0][0], p0[0][1]), fmaxf(p0[0][2], p0[0][3])),
                               fmaxf(fmaxf(p0[1][0], p0[1][1]), fmaxf(p0[1][2], p0[1][3])));
            tmax = fmaxf(tmax, fmaxf(fmaxf(fmaxf(p0[2][0], p0[2][1]), fmaxf(p0[2][2], p0[2][3])),
                                     fmaxf(fmaxf(p0[3][0], p0[3][1]), fmaxf(p0[3][2], p0[3][3]))));
            tmax = kbmax4(tmax);
            if (__any(tmax - Mr0 > 11.5415605f)) {
                float nM = fmaxf(Mr0, tmax);
                float scf = fexp2(Mr0 - nM);
                Mr0 = nM;
                Lr0 *= scf;
                float s0 = __int_as_float(__builtin_amdgcn_ds_bpermute(idxr[0], __float_as_int(scf)));
                float s1 = __int_as_float(__builtin_amdgcn_ds_bpermute(idxr[1], __float_as_int(scf)));
                float s2 = __int_as_float(__builtin_amdgcn_ds_bpermute(idxr[2], __float_as_int(scf)));
                float s3 = __int_as_float(__builtin_amdgcn_ds_bpermute(idxr[3], __float_as_int(scf)));
#pragma unroll
                for (int dt = 0; dt < 4; ++dt) {
                    oacc0[dt][0] *= s0; oacc0[dt][1] *= s1;
                    oacc0[dt][2] *= s2; oacc0[dt][3] *= s3;
                }
            }
            float ps = 0.f;
#pragma unroll
            for (int nt = 0; nt < 4; ++nt)
#pragma unroll
                for (int r = 0; r < 4; ++r) {
                    float e = fexp2(p0[nt][r] - Mr0);
                    p0[nt][r] = e;
                    ps += e;
                }
            ps = kbsum4(ps);
            Lr0 += ps;
#pragma unroll
            for (int k2 = 0; k2 < 2; ++k2) {
#pragma unroll
                for (int j = 0; j < 4; ++j) {
                    float x = p0[2 * k2 + (j >> 1)][(j & 1) * 2];
                    float y = p0[2 * k2 + (j >> 1)][(j & 1) * 2 + 1];
                    unsigned hw2 = cvtpk(x, y);
                    pah0[k2].w[j] = hw2;
                    float lx = x - __uint_as_float(hw2 << 16);
                    float ly = y - __uint_as_float(hw2 & 0xFFFF0000u);
                    pal0[k2].w[j] = cvtpk(lx, ly);
                }
            }
        }
        // ---- softmax row-group 1 ----
        {
            float tmax = fmaxf(fmaxf(fmaxf(p1[0][0], p1[0][1]), fmaxf(p1[0][2], p1[0][3])),
                               fmaxf(fmaxf(p1[1][0], p1[1][1]), fmaxf(p1[1][2], p1[1][3])));
            tmax = fmaxf(tmax, fmaxf(fmaxf(fmaxf(p1[2][0], p1[2][1]), fmaxf(p1[2][2], p1[2][3])),
                                     fmaxf(fmaxf(p1[3][0], p1[3][1]), fmaxf(p1[3][2], p1[3][3]))));
            tmax = kbmax4(tmax);
            if (__any(tmax - Mr1 > 11.5415605f)) {
                float nM = fmaxf(Mr1, tmax);
                float scf = fexp2(Mr1 - nM);
                Mr1 = nM;
                Lr1 *= scf;
                float s0 = __int_as_float(__builtin_amdgcn_ds_bpermute(idxr[0], __float_as_int(scf)));
                float s1 = __int_as_float(__builtin_amdgcn_ds_bpermute(idxr[1], __float_as_int(scf)));
                float s2 = __int_as_float(__builtin_amdgcn_ds_bpermute(idxr[2], __float_as_int(scf)));
                float s3 = __int_as_float(__builtin_amdgcn_ds_bpermute(idxr[3], __float_as_int(scf)));
#pragma unroll
                for (int dt = 0; dt < 4; ++dt) {
                    oacc1[dt][0] *= s0; oacc1[dt][1] *= s1;
                    oacc1[dt][2] *= s2; oacc1[dt][3] *= s3;
                }
            }
            float ps = 0.f;
#pragma unroll
            for (int nt = 0; nt < 4; ++nt)
#pragma unroll
                for (int r = 0; r < 4; ++r) {
                    float e = fexp2(p1[nt][r] - Mr1);
                    p1[nt][r] = e;
                    ps += e;
                }
            ps = kbsum4(ps);
            Lr1 += ps;
#pragma unroll
            for (int k2 = 0; k2 < 2; ++k2) {
#pragma unroll
                for (int j = 0; j < 4; ++j) {
                    float x = p1[2 * k2 + (j >> 1)][(j & 1) * 2];
                    float y = p1[2 * k2 + (j >> 1)][(j & 1) * 2 + 1];
                    unsigned hw2 = cvtpk(x, y);
                    pah1[k2].w[j] = hw2;
                    float lx = x - __uint_as_float(hw2 << 16);
                    float ly = y - __uint_as_float(hw2 & 0xFFFF0000u);
                    pal1[k2].w[j] = cvtpk(lx, ly);
                }
            }
        }
        // ---- PV: shared V fragment reads feed both row-groups ----
        __builtin_amdgcn_s_setprio(1);
#pragma unroll
        for (int dt = 0; dt < 4; ++dt) {
#pragma unroll
            for (int k2 = 0; k2 < 2; ++k2) {
                s8v vh2 = *(const s8v*)&Vh[buf][dt * 16 + l15][k2 * 32 + kb * 8];
                s8v vl2 = *(const s8v*)&Vl[buf][dt * 16 + l15][k2 * 32 + kb * 8];
                oacc0[dt] = BMFMA(pah0[k2].v, vh2, oacc0[dt]);
                oacc0[dt] = BMFMA(pah0[k2].v, vl2, oacc0[dt]);
                oacc0[dt] = BMFMA(pal0[k2].v, vh2, oacc0[dt]);
                oacc1[dt] = BMFMA(pah1[k2].v, vh2, oacc1[dt]);
                oacc1[dt] = BMFMA(pah1[k2].v, vl2, oacc1[dt]);
                oacc1[dt] = BMFMA(pal1[k2].v, vh2, oacc1[dt]);
            }
        }
        __builtin_amdgcn_s_setprio(0);
    }
#undef P2_LOAD
    // ---- epilogue rg0 ----
    {
        float i0 = 1.f / __int_as_float(__builtin_amdgcn_ds_bpermute(idxr[0], __float_as_int(Lr0)));
        float i1 = 1.f / __int_as_float(__builtin_amdgcn_ds_bpermute(idxr[1], __float_as_int(Lr0)));
        float i2 = 1.f / __int_as_float(__builtin_amdgcn_ds_bpermute(idxr[2], __float_as_int(Lr0)));
        float i3 = 1.f / __int_as_float(__builtin_amdgcn_ds_bpermute(idxr[3], __float_as_int(Lr0)));
        float inv_r[4] = {i0, i1, i2, i3};
#pragma unroll
        for (int dt = 0; dt < 4; ++dt)
#pragma unroll
            for (int r = 0; r < 4; ++r) {
                float o = oacc0[dt][r] * inv_r[r];
                unsigned short hi, lo;
                bsplit(o, hi, lo);
                long long idx = ((long long)(b * N_ + n0 + w * 32 + kb * 4 + r)) * DIMM
                              + h * 64 + dt * 16 + l15;
                attn_hi[idx] = hi;
                attn_lo[idx] = lo;
            }
    }
    // ---- epilogue rg1 ----
    {
        float i0 = 1.f / __int_as_float(__builtin_amdgcn_ds_bpermute(idxr[0], __float_as_int(Lr1)));
        float i1 = 1.f / __int_as_float(__builtin_amdgcn_ds_bpermute(idxr[1], __float_as_int(Lr1)));
        float i2 = 1.f / __int_as_float(__builtin_amdgcn_ds_bpermute(idxr[2], __float_as_int(Lr1)));
        float i3 = 1.f / __int_as_float(__builtin_amdgcn_ds_bpermute(idxr[3], __float_as_int(Lr1)));
        float inv_r[4] = {i0, i1, i2, i3};
#pragma unroll
        for (int dt = 0; dt < 4; ++dt)
#pragma unroll
            for (int r = 0; r < 4; ++r) {
                float o = oacc1[dt][r] * inv_r[r];
                unsigned short hi, lo;
                bsplit(o, hi, lo);
                long long idx = ((long long)(b * N_ + n0 + w * 32 + 16 + kb * 4 + r)) * DIMM
                              + h * 64 + dt * 16 + l15;
                attn_hi[idx] = hi;
                attn_lo[idx] = lo;
            }
    }
}

// ---------------- K6: output GEMM, 128x128 blocks, single-buf swizzled LDS ----------------
__global__ __launch_bounds__(256) void k_gemm_out(
    const unsigned short* __restrict__ Ahi, const unsigned short* __restrict__ Alo,
    const unsigned short* __restrict__ Wothi, const unsigned short* __restrict__ Wotlo,
    const float* __restrict__ bias, float* __restrict__ out)
{
    int row0 = blockIdx.x * 128, j0 = blockIdx.y * 128;
    __shared__ unsigned short Ah[128][32], Al[128][32];
    __shared__ unsigned short Bh[128][32], Bl[128][32];
    int t = threadIdx.x;
    int w = t >> 6, lane = t & 63, l15 = lane & 15, kb = lane >> 4;
    int srow = t >> 1, sseg = t & 1;
    int sw = (srow >> 1) & 3;
    int c0 = ((2 * sseg + 0) ^ sw) * 8;
    int c1 = ((2 * sseg + 1) ^ sw) * 8;
    int rs = (l15 >> 1) & 3;
    int rb = (kb ^ rs) * 8;
    f4v acc[2][8];
#pragma unroll
    for (int rt = 0; rt < 2; ++rt)
#pragma unroll
        for (int dt = 0; dt < 8; ++dt) acc[rt][dt] = (f4v){0.f, 0.f, 0.f, 0.f};
    uint4 a0, a1, al0, al1, b0, b1, bl0, bl1;
#define GOUT_LOAD(KC) { \
    int kO = (KC) * 32 + sseg * 16; \
    const unsigned short* ap  = Ahi + (long long)(row0 + srow) * DIMM + kO; \
    const unsigned short* alp = Alo + (long long)(row0 + srow) * DIMM + kO; \
    a0 = *(const uint4*)ap;  a1 = *(const uint4*)(ap + 8); \
    al0 = *(const uint4*)alp; al1 = *(const uint4*)(alp + 8); \
    const unsigned short* bp  = Wothi + (long long)(j0 + srow) * DIMM + kO; \
    const unsigned short* blp = Wotlo + (long long)(j0 + srow) * DIMM + kO; \
    b0 = *(const uint4*)bp;  b1 = *(const uint4*)(bp + 8); \
    bl0 = *(const uint4*)blp; bl1 = *(const uint4*)(blp + 8); }

    GOUT_LOAD(0)
    for (int kc = 0; kc < 16; ++kc) {
        *(uint4*)&Ah[srow][c0] = a0;
        *(uint4*)&Ah[srow][c1] = a1;
        *(uint4*)&Al[srow][c0] = al0;
        *(uint4*)&Al[srow][c1] = al1;
        *(uint4*)&Bh[srow][c0] = b0;
        *(uint4*)&Bh[srow][c1] = b1;
        *(uint4*)&Bl[srow][c0] = bl0;
        *(uint4*)&Bl[srow][c1] = bl1;
        __syncthreads();
        if (kc < 15) { GOUT_LOAD(kc + 1) }
        fragu ah[2], al2[2];
#pragma unroll
        for (int rt = 0; rt < 2; ++rt) {
            ah[rt].v  = *(const s8v*)&Ah[w * 32 + rt * 16 + l15][rb];
            al2[rt].v = *(const s8v*)&Al[w * 32 + rt * 16 + l15][rb];
        }
#pragma unroll
        for (int dt = 0; dt < 8; ++dt) {
            s8v bh = *(const s8v*)&Bh[dt * 16 + l15][rb];
            s8v bl = *(const s8v*)&Bl[dt * 16 + l15][rb];
#pragma unroll
            for (int rt = 0; rt < 2; ++rt) {
                acc[rt][dt] = BMFMA(ah[rt].v, bh, acc[rt][dt]);
                acc[rt][dt] = BMFMA(ah[rt].v, bl, acc[rt][dt]);
                acc[rt][dt] = BMFMA(al2[rt].v, bh, acc[rt][dt]);
            }
        }
        __syncthreads();
    }
#undef GOUT_LOAD
#pragma unroll
    for (int dt = 0; dt < 8; ++dt) {
        float bv = bias[j0 + dt * 16 + l15];
#pragma unroll
        for (int rt = 0; rt < 2; ++rt)
#pragma unroll
            for (int r = 0; r < 4; ++r)
                out[(long long)(row0 + w * 32 + rt * 16 + kb * 4 + r) * DIMM + j0 + dt * 16 + l15]
                    = acc[rt][dt][r] + bv;
    }
}

extern "C" void kernel_launch(void* const* d_in, const int* in_sizes, int n_in,
                              void* d_out, int out_size, void* d_ws, size_t ws_size,
                              hipStream_t stream) {
    (void)in_sizes; (void)n_in; (void)out_size; (void)ws_size;
    const float* q      = (const float*)d_in[0];
    const float* k      = (const float*)d_in[1];
    const float* v      = (const float*)d_in[2];
    const float* ln_g   = (const float*)d_in[3];
    const float* ln_b   = (const float*)d_in[4];
    const float* W_in   = (const float*)d_in[5];
    const float* wp_W1  = (const float*)d_in[6];
    const float* wp_b1  = (const float*)d_in[7];
    const float* wp_lng = (const float*)d_in[8];
    const float* wp_lnb = (const float*)d_in[9];
    const float* wp_W2  = (const float*)d_in[10];
    const float* wp_b2  = (const float*)d_in[11];
    const float* wp_W3  = (const float*)d_in[12];
    const float* wp_b3  = (const float*)d_in[13];
    const float* wtemp  = (const float*)d_in[14];
    const float* W_out  = (const float*)d_in[15];
    const float* b_out  = (const float*)d_in[16];
    float* out = (float*)d_out;

    char* w = (char*)d_ws;
    unsigned short* attn_hi = (unsigned short*)(w + 0);
    unsigned short* attn_lo = (unsigned short*)(w + 8388608);
    unsigned short* Fqhi  = (unsigned short*)(w + 16777216);
    unsigned short* Fqlo  = (unsigned short*)(w + 25165824);
    unsigned short* Fkhi  = (unsigned short*)(w + 33554432);
    unsigned short* Fklo  = (unsigned short*)(w + 41943040);
    unsigned short* Fvthi = (unsigned short*)(w + 50331648);
    unsigned short* Fvtlo = (unsigned short*)(w + 58720256);
    unsigned short* Wthi  = (unsigned short*)(w + 67108864);
    unsigned short* Wtlo  = (unsigned short*)(w + 67633152);
    unsigned short* Wothi = (unsigned short*)(w + 68157440);
    unsigned short* Wotlo = (unsigned short*)(w + 68681728);
    float* muv  = (float*)(w + 69206016);
    float* rsd  = (float*)(w + 69304320);
    float* qinv = (float*)(w + 69402624);
    float* mq   = (float*)(w + 69664768);
    float* gv   = (float*)(w + 69926912);
    float* kinv = (float*)(w + 70189056);
    float* ks   = (float*)(w + 70451200);
    float* vc   = (float*)(w + 70713344);
    float* rowA = (float*)(w + 70975488);
    float* rowB = (float*)(w + 71237632);   // (unused, kept for layout stability)
    float* rowM = (float*)(w + 71499776);
    float* csq  = (float*)(w + 71761920);
    float* csk  = (float*)(w + 71778304);
    double* acc = (double*)(w + 71794688);
    float* wb   = (float*)(w + 71796736);
    float* scl  = (float*)(w + 71796864);
    unsigned* ticket = (unsigned*)(w + 71794688 + 768);  // inside zeroed acc slab
    float* c1b  = (float*)(w + 71797504);   // 512 floats
    float* c2b  = (float*)(w + 71799552);   // 512 floats
    (void)rowB;

    // zero rowA/rowB/rowM (3 x 256KB) + csq/csk (2 x 16KB) + accum/ticket slab
    hipMemsetAsync(rowA, 0, 3 * 262144 + 2 * 16384 + 2048, stream);

    k_prep<<<6280, 256, 0, stream>>>(q, k, v, muv, rsd, W_in, W_out, Wthi, Wtlo, Wothi, Wotlo,
                                     ln_g, ln_b, c1b, c2b);
    k_gemm_in<<<dim3(64, 4, 3), 256, 0, stream>>>(q, k, v, muv, rsd, c1b, c2b,
                                                  Wthi, Wtlo, Fqhi, Fqlo, Fkhi, Fklo, Fvthi, Fvtlo,
                                                  qinv, mq, kinv, ks, csq, csk);
    k_gvec_mlp<<<129, 512, 0, stream>>>(Fqhi, Fqlo, csk, mq, gv, csq,
                                        wp_W1, wp_b1, wp_lng, wp_lnb, wp_W2, wp_b2, wp_W3, wp_b3,
                                        wtemp, wb);
    k_pass1<<<4096, 256, 0, stream>>>(Fqhi, Fkhi, qinv, mq, gv, kinv, ks, rowA, rowM, acc);
    k_rowfin<<<64, 256, 0, stream>>>(rowA, rowM, vc, acc, wb, scl, ticket);
    k_pass2<<<256, 512, 0, stream>>>(Fqhi, Fqlo, Fkhi, Fklo, Fvthi, Fvtlo,
                                     qinv, mq, gv, kinv, ks, vc, scl, attn_hi, attn_lo);
    k_gemm_out<<<dim3(64, 4), 256, 0, stream>>>(attn_hi, attn_lo, Wothi, Wotlo, b_out, out);
}

// Round 8
// 214.269 us; speedup vs baseline: 1.0406x; 1.0406x over previous
//
#include <hip/hip_runtime.h>
#include <math.h>

#define H_ 8
#define B_ 8
#define N_ 1024
#define D_ 64
#define DIMM 512
#define NROWS 8192

typedef __attribute__((ext_vector_type(8))) short s8v;
typedef __attribute__((ext_vector_type(4))) float f4v;
typedef __attribute__((ext_vector_type(2))) unsigned int u2v;
union fragu { s8v v; unsigned int w[4]; uint4 q; };

#define BMFMA(a, b, c) __builtin_amdgcn_mfma_f32_16x16x32_bf16(a, b, c, 0, 0, 0)

__device__ __forceinline__ float wred_sum(float v) {
#pragma unroll
    for (int m = 32; m >= 1; m >>= 1) v += __shfl_xor(v, m, 64);
    return v;
}
__device__ __forceinline__ double wred_sum_d(double v) {
#pragma unroll
    for (int m = 32; m >= 1; m >>= 1) v += __shfl_xor(v, m, 64);
    return v;
}
// packed RN bf16 convert: low16 = bf16(a), high16 = bf16(b)
__device__ __forceinline__ unsigned cvtpk(float a, float b) {
    unsigned r;
    asm("v_cvt_pk_bf16_f32 %0, %1, %2" : "=v"(r) : "v"(a), "v"(b));
    return r;
}
// RN split: a ~= hi + lo (both RN bf16)
__device__ __forceinline__ void bsplit(float a, unsigned short& hi, unsigned short& lo) {
    unsigned h = cvtpk(a, 0.f);
    hi = (unsigned short)h;
    float r = a - __uint_as_float(h << 16);
    lo = (unsigned short)cvtpk(r, 0.f);
}
// split 8 f32 -> 4 packed u32 RN-hi pairs + 4 packed u32 RN-lo pairs
__device__ __forceinline__ void split8(const float* a, unsigned* hw, unsigned* lw) {
#pragma unroll
    for (int i = 0; i < 4; ++i) {
        unsigned h = cvtpk(a[2 * i], a[2 * i + 1]);
        hw[i] = h;
        float l0 = a[2 * i]     - __uint_as_float(h << 16);
        float l1 = a[2 * i + 1] - __uint_as_float(h & 0xFFFF0000u);
        lw[i] = cvtpk(l0, l1);
    }
}

// fast 2^x (v_exp_f32 IS 2^x)
__device__ __forceinline__ float fexp2(float x) {
#if __has_builtin(__builtin_amdgcn_exp2f)
    return __builtin_amdgcn_exp2f(x);
#else
    return exp2f(x);
#endif
}

#if __has_builtin(__builtin_amdgcn_permlane16_swap) && __has_builtin(__builtin_amdgcn_permlane32_swap)
#define HAVE_PLSWAP 1
#endif

// max over the 4 lanes {l, l^16, l^32, l^48} — VALU-only (no DS pipe)
__device__ __forceinline__ float kbmax4(float x) {
#ifdef HAVE_PLSWAP
    u2v a = __builtin_amdgcn_permlane16_swap(__float_as_uint(x), __float_as_uint(x), false, false);
    float m = fmaxf(__uint_as_float(a[0]), __uint_as_float(a[1]));
    u2v c = __builtin_amdgcn_permlane32_swap(__float_as_uint(m), __float_as_uint(m), false, false);
    return fmaxf(__uint_as_float(c[0]), __uint_as_float(c[1]));
#else
    x = fmaxf(x, __shfl_xor(x, 16, 64));
    return fmaxf(x, __shfl_xor(x, 32, 64));
#endif
}
// sum over the 4 lanes {l, l^16, l^32, l^48} — VALU-only
__device__ __forceinline__ float kbsum4(float x) {
#ifdef HAVE_PLSWAP
    u2v a = __builtin_amdgcn_permlane16_swap(__float_as_uint(x), __float_as_uint(x), false, false);
    float m = __uint_as_float(a[0]) + __uint_as_float(a[1]);
    u2v c = __builtin_amdgcn_permlane32_swap(__float_as_uint(m), __float_as_uint(m), false, false);
    return __uint_as_float(c[0]) + __uint_as_float(c[1]);
#else
    x += __shfl_xor(x, 16, 64);
    x += __shfl_xor(x, 32, 64);
    return x;
#endif
}

// ---------------- K0: fused per-row LN stats (q,k,v) + W transpose/split ----------------
__global__ __launch_bounds__(256) void k_prep(
    const float* __restrict__ q, const float* __restrict__ k, const float* __restrict__ v,
    float* __restrict__ muv, float* __restrict__ rsd,
    const float* __restrict__ Win, const float* __restrict__ Wout,
    unsigned short* __restrict__ Wthi, unsigned short* __restrict__ Wtlo,
    unsigned short* __restrict__ Wothi, unsigned short* __restrict__ Wotlo)
{
    int bx = blockIdx.x;
    __shared__ float S[64][65];
    int t = threadIdx.x;
    if (bx < 6144) {
        int w = t >> 6, lane = t & 63;
        int row = bx * 4 + w;
        int tens = row >> 13;
        int lrow = row & 8191;
        const float* src = (tens == 0) ? q : (tens == 1 ? k : v);
        const float* p = src + (long long)lrow * DIMM + lane * 8;
        float4 a = *(const float4*)p;
        float4 b = *(const float4*)(p + 4);
        float s  = a.x + a.y + a.z + a.w + b.x + b.y + b.z + b.w;
        float sq = a.x*a.x + a.y*a.y + a.z*a.z + a.w*a.w + b.x*b.x + b.y*b.y + b.z*b.z + b.w*b.w;
        s = wred_sum(s); sq = wred_sum(sq);
        if (lane == 0) {
            float m = s * (1.f / 512.f);
            float var = sq * (1.f / 512.f) - m * m;
            muv[row] = m;
            rsd[row] = rsqrtf(var + 1e-5f);
        }
        return;
    }
    int sb = bx - 6144;          // 0..127: [z][jx][kx]
    int z = sb >> 6;
    int rem = sb & 63;
    int kxi = rem & 7, jxi = rem >> 3;
    const float* Wsrc = z ? Wout : Win;
    unsigned short* Dhi = z ? Wothi : Wthi;
    unsigned short* Dlo = z ? Wotlo : Wtlo;
    int k0 = kxi * 64, j0 = jxi * 64;
    int rr = t >> 2, seg = t & 3;
    const float* p = Wsrc + (long long)(k0 + rr) * DIMM + j0 + seg * 16;
    float4 a0 = *(const float4*)p, a1 = *(const float4*)(p + 4),
           a2 = *(const float4*)(p + 8), a3 = *(const float4*)(p + 12);
    S[rr][seg*16+ 0]=a0.x; S[rr][seg*16+ 1]=a0.y; S[rr][seg*16+ 2]=a0.z; S[rr][seg*16+ 3]=a0.w;
    S[rr][seg*16+ 4]=a1.x; S[rr][seg*16+ 5]=a1.y; S[rr][seg*16+ 6]=a1.z; S[rr][seg*16+ 7]=a1.w;
    S[rr][seg*16+ 8]=a2.x; S[rr][seg*16+ 9]=a2.y; S[rr][seg*16+10]=a2.z; S[rr][seg*16+11]=a2.w;
    S[rr][seg*16+12]=a3.x; S[rr][seg*16+13]=a3.y; S[rr][seg*16+14]=a3.z; S[rr][seg*16+15]=a3.w;
    __syncthreads();
    float f[16];
#pragma unroll
    for (int i = 0; i < 16; ++i) f[i] = S[seg * 16 + i][rr];
    unsigned hw[8], lw[8];
    split8(f, hw, lw);
    split8(f + 8, hw + 4, lw + 4);
    long long ob = (long long)(j0 + rr) * DIMM + k0 + seg * 16;
    *(uint4*)&Dhi[ob]     = make_uint4(hw[0], hw[1], hw[2], hw[3]);
    *(uint4*)&Dhi[ob + 8] = make_uint4(hw[4], hw[5], hw[6], hw[7]);
    *(uint4*)&Dlo[ob]     = make_uint4(lw[0], lw[1], lw[2], lw[3]);
    *(uint4*)&Dlo[ob + 8] = make_uint4(lw[4], lw[5], lw[6], lw[7]);
}

// ---------------- K1: fused LN + input projection, 128x128 blocks ----------------
// Wave repartition: each wave owns a 64x64 output tile (rows (w&1)*64 + rt*16,
// cols (w>>1)*64 + dt*16) -> LDS frag reads/wave-iter 20 -> 16 (A 8 + B 8).
__global__ __launch_bounds__(256) void k_gemm_in(
    const float* __restrict__ qx, const float* __restrict__ kx, const float* __restrict__ vx,
    const float* __restrict__ muv, const float* __restrict__ rsd,
    const float* __restrict__ lng, const float* __restrict__ lnb,
    const unsigned short* __restrict__ Wthi, const unsigned short* __restrict__ Wtlo,
    unsigned short* __restrict__ Fqhi, unsigned short* __restrict__ Fqlo,
    unsigned short* __restrict__ Fkhi, unsigned short* __restrict__ Fklo,
    unsigned short* __restrict__ Fvthi, unsigned short* __restrict__ Fvtlo,
    float* __restrict__ qinv, float* __restrict__ mq,
    float* __restrict__ kinv, float* __restrict__ ks,
    float* __restrict__ csq, float* __restrict__ csk)
{
    int tens = blockIdx.z;
    const float* X = (tens == 0) ? qx : (tens == 1 ? kx : vx);
    int row0 = blockIdx.x * 128, hq = blockIdx.y;
    const float* muT = muv + tens * NROWS;
    const float* rsT = rsd + tens * NROWS;
    __shared__ unsigned short Ah[128][32], Al[128][32];
    __shared__ unsigned short Bh[128][32], Bl[128][32];
    int t = threadIdx.x;
    int w = t >> 6, lane = t & 63, l15 = lane & 15, kb = lane >> 4;
    int srow = t >> 1, sseg = t & 1;
    int sw = (srow >> 1) & 3;                 // write-side swizzle
    int c0 = ((2 * sseg + 0) ^ sw) * 8;
    int c1 = ((2 * sseg + 1) ^ sw) * 8;
    int rs = (l15 >> 1) & 3;                  // read-side swizzle (row mod-4 drops out)
    int rb = (kb ^ rs) * 8;
    int rhalf = (w & 1) * 64;                 // wave's row half
    int chalf = (w >> 1) * 64;                // wave's col half (head half)
    float amu = muT[row0 + srow], ars = rsT[row0 + srow];
    f4v acc[4][4];
#pragma unroll
    for (int rt = 0; rt < 4; ++rt)
#pragma unroll
        for (int dt = 0; dt < 4; ++dt) acc[rt][dt] = (f4v){0.f, 0.f, 0.f, 0.f};

    float4 x0, x1, x2, x3, g0, g1, g2, g3, cc0, cc1, cc2, cc3;
    uint4 wh0, wh1, wl0, wl1;
#define GIN_LOAD(KC) { \
    int kO = (KC) * 32 + sseg * 16; \
    const float* xp = X + (long long)(row0 + srow) * DIMM + kO; \
    x0 = *(const float4*)xp;       x1 = *(const float4*)(xp + 4); \
    x2 = *(const float4*)(xp + 8); x3 = *(const float4*)(xp + 12); \
    g0 = *(const float4*)(lng + kO);     g1 = *(const float4*)(lng + kO + 4); \
    g2 = *(const float4*)(lng + kO + 8); g3 = *(const float4*)(lng + kO + 12); \
    cc0 = *(const float4*)(lnb + kO);     cc1 = *(const float4*)(lnb + kO + 4); \
    cc2 = *(const float4*)(lnb + kO + 8); cc3 = *(const float4*)(lnb + kO + 12); \
    const unsigned short* wph = Wthi + (long long)(hq * 128 + srow) * DIMM + kO; \
    const unsigned short* wpl = Wtlo + (long long)(hq * 128 + srow) * DIMM + kO; \
    wh0 = *(const uint4*)wph; wh1 = *(const uint4*)(wph + 8); \
    wl0 = *(const uint4*)wpl; wl1 = *(const uint4*)(wpl + 8); }

    GIN_LOAD(0)
    for (int kc = 0; kc < 16; ++kc) {
        float av[16];
        av[ 0]=fmaf((x0.x-amu)*ars,g0.x,cc0.x); av[ 1]=fmaf((x0.y-amu)*ars,g0.y,cc0.y);
        av[ 2]=fmaf((x0.z-amu)*ars,g0.z,cc0.z); av[ 3]=fmaf((x0.w-amu)*ars,g0.w,cc0.w);
        av[ 4]=fmaf((x1.x-amu)*ars,g1.x,cc1.x); av[ 5]=fmaf((x1.y-amu)*ars,g1.y,cc1.y);
        av[ 6]=fmaf((x1.z-amu)*ars,g1.z,cc1.z); av[ 7]=fmaf((x1.w-amu)*ars,g1.w,cc1.w);
        av[ 8]=fmaf((x2.x-amu)*ars,g2.x,cc2.x); av[ 9]=fmaf((x2.y-amu)*ars,g2.y,cc2.y);
        av[10]=fmaf((x2.z-amu)*ars,g2.z,cc2.z); av[11]=fmaf((x2.w-amu)*ars,g2.w,cc2.w);
        av[12]=fmaf((x3.x-amu)*ars,g3.x,cc3.x); av[13]=fmaf((x3.y-amu)*ars,g3.y,cc3.y);
        av[14]=fmaf((x3.z-amu)*ars,g3.z,cc3.z); av[15]=fmaf((x3.w-amu)*ars,g3.w,cc3.w);
        unsigned hw[8], lw[8];
        split8(av, hw, lw);
        split8(av + 8, hw + 4, lw + 4);
        *(uint4*)&Ah[srow][c0] = make_uint4(hw[0], hw[1], hw[2], hw[3]);
        *(uint4*)&Ah[srow][c1] = make_uint4(hw[4], hw[5], hw[6], hw[7]);
        *(uint4*)&Al[srow][c0] = make_uint4(lw[0], lw[1], lw[2], lw[3]);
        *(uint4*)&Al[srow][c1] = make_uint4(lw[4], lw[5], lw[6], lw[7]);
        *(uint4*)&Bh[srow][c0] = wh0;
        *(uint4*)&Bh[srow][c1] = wh1;
        *(uint4*)&Bl[srow][c0] = wl0;
        *(uint4*)&Bl[srow][c1] = wl1;
        __syncthreads();
        if (kc < 15) { GIN_LOAD(kc + 1) }   // overlap next-tile loads with MFMA
        fragu ah[4], al2[4];
#pragma unroll
        for (int rt = 0; rt < 4; ++rt) {
            ah[rt].v  = *(const s8v*)&Ah[rhalf + rt * 16 + l15][rb];
            al2[rt].v = *(const s8v*)&Al[rhalf + rt * 16 + l15][rb];
        }
#pragma unroll
        for (int dt = 0; dt < 4; ++dt) {
            s8v bh = *(const s8v*)&Bh[chalf + dt * 16 + l15][rb];
            s8v bl = *(const s8v*)&Bl[chalf + dt * 16 + l15][rb];
#pragma unroll
            for (int rt = 0; rt < 4; ++rt) {
                acc[rt][dt] = BMFMA(ah[rt].v, bh, acc[rt][dt]);
                acc[rt][dt] = BMFMA(ah[rt].v, bl, acc[rt][dt]);
                acc[rt][dt] = BMFMA(al2[rt].v, bh, acc[rt][dt]);
            }
        }
        __syncthreads();
    }
#undef GIN_LOAD
    int b = row0 >> 10;
    int hbx = (hq * 2 + (w >> 1)) * 8 + b;    // wave's head-block
    if (tens < 2) {
        unsigned short* Dh = tens ? Fkhi : Fqhi;
        unsigned short* Dl = tens ? Fklo : Fqlo;
#pragma unroll
        for (int rt = 0; rt < 4; ++rt) {
            int nloc = (row0 & 1023) + rhalf + rt * 16 + kb * 4;
#pragma unroll
            for (int dt = 0; dt < 4; ++dt) {
#pragma unroll
                for (int r = 0; r < 4; ++r) {
                    unsigned short hi, lo;
                    bsplit(acc[rt][dt][r], hi, lo);
                    long long idx = ((long long)hbx * N_ + nloc + r) * D_ + dt * 16 + l15;
                    Dh[idx] = hi;
                    Dl[idx] = lo;
                }
            }
#pragma unroll
            for (int r = 0; r < 4; ++r) {
                float a0 = acc[rt][0][r], a1 = acc[rt][1][r],
                      a2 = acc[rt][2][r], a3 = acc[rt][3][r];
                float s  = a0 + a1 + a2 + a3;
                float sq = a0*a0 + a1*a1 + a2*a2 + a3*a3;
#pragma unroll
                for (int msk = 8; msk >= 1; msk >>= 1) {
                    s  += __shfl_xor(s, msk, 64);
                    sq += __shfl_xor(sq, msk, 64);
                }
                if (l15 == 0) {
                    int rowg = hbx * N_ + nloc + r;
                    float inv = 1.f / (sqrtf(sq) + 1e-6f);
                    if (tens) { kinv[rowg] = inv; ks[rowg] = s; }
                    else      { qinv[rowg] = inv; mq[rowg] = s * (1.f / 64.f); }
                }
            }
        }
        float* cs = tens ? csk : csq;
#pragma unroll
        for (int dt = 0; dt < 4; ++dt) {
            float c = acc[0][dt][0] + acc[0][dt][1] + acc[0][dt][2] + acc[0][dt][3]
                    + acc[1][dt][0] + acc[1][dt][1] + acc[1][dt][2] + acc[1][dt][3]
                    + acc[2][dt][0] + acc[2][dt][1] + acc[2][dt][2] + acc[2][dt][3]
                    + acc[3][dt][0] + acc[3][dt][1] + acc[3][dt][2] + acc[3][dt][3];
            c += __shfl_xor(c, 16, 64);
            c += __shfl_xor(c, 32, 64);
            if (kb == 0) atomicAdd(&cs[hbx * 64 + dt * 16 + l15], c);
        }
    } else {
        // V^T store with the SAME phi-permutation per 64-key tile:
        // within-tile idx = rt*16 + kb*4 + r -> pos (rt>>1)*32 + kb*8 + (rt&1)*4 + r
#pragma unroll
        for (int dt = 0; dt < 4; ++dt) {
#pragma unroll
            for (int rt = 0; rt < 4; ++rt) {
                int vcol = (row0 & 1023) + rhalf + (rt >> 1) * 32 + (kb << 3) + ((rt & 1) << 2);
                unsigned short hh4[4], ll4[4];
#pragma unroll
                for (int r = 0; r < 4; ++r) bsplit(acc[rt][dt][r], hh4[r], ll4[r]);
                long long idx = ((long long)hbx * D_ + dt * 16 + l15) * N_ + vcol;
                *(uint2*)&Fvthi[idx] = make_uint2((unsigned)hh4[0] | ((unsigned)hh4[1] << 16),
                                                  (unsigned)hh4[2] | ((unsigned)hh4[3] << 16));
                *(uint2*)&Fvtlo[idx] = make_uint2((unsigned)ll4[0] | ((unsigned)ll4[1] << 16),
                                                  (unsigned)ll4[2] | ((unsigned)ll4[3] << 16));
            }
        }
    }
}

// ---------------- K2: fused g-vector + weight-predictor MLP (one launch) ----------------
__global__ __launch_bounds__(512) void k_gvec_mlp(
    const unsigned short* __restrict__ Fqhi, const unsigned short* __restrict__ Fqlo,
    const float* __restrict__ csk, const float* __restrict__ mq, float* __restrict__ g,
    const float* __restrict__ csq,
    const float* __restrict__ W1, const float* __restrict__ b1,
    const float* __restrict__ lg, const float* __restrict__ lb,
    const float* __restrict__ W2, const float* __restrict__ b2,
    const float* __restrict__ W3, const float* __restrict__ b3,
    const float* __restrict__ wtemp, float* __restrict__ wbuf)
{
    int bx = blockIdx.x;
    int t = threadIdx.x;
    if (bx < 128) {
        __shared__ float mk[64];
        __shared__ float smkv;
        int hb = bx >> 1;
        int r0 = (bx & 1) * 512;
        if (t < 64) mk[t] = csk[hb * 64 + t] * (1.f / 1024.f);
        __syncthreads();
        if (t == 0) {
            float s = 0;
            for (int i = 0; i < 64; ++i) s += mk[i];
            smkv = s;
        }
        __syncthreads();
        float smk = smkv;
        int rowg = hb * N_ + r0 + t;
        const uint4* ph = (const uint4*)(Fqhi + (long long)rowg * D_);
        const uint4* pl = (const uint4*)(Fqlo + (long long)rowg * D_);
        float acc = 0.f;
#pragma unroll
        for (int i = 0; i < 8; ++i) {
            uint4 hh = ph[i];
            uint4 ll = pl[i];
            const unsigned* hu = &hh.x;
            const unsigned* lu = &ll.x;
#pragma unroll
            for (int j = 0; j < 4; ++j) {
                float v0 = __uint_as_float((hu[j] & 0xFFFFu) << 16) + __uint_as_float((lu[j] & 0xFFFFu) << 16);
                float v1 = __uint_as_float(hu[j] & 0xFFFF0000u) + __uint_as_float(lu[j] & 0xFFFF0000u);
                acc = fmaf(v0, mk[i * 8 + j * 2], acc);
                acc = fmaf(v1, mk[i * 8 + j * 2 + 1], acc);
            }
        }
        g[rowg] = acc - mq[rowg] * smk;
        return;
    }
    // ---- MLP (one block, 512 threads) ----
    __shared__ float cat[8][128];
    __shared__ float z1[8][64];
    __shared__ float zr[8][64];
    __shared__ float z2[8][32];
    __shared__ float z3[8][3];
    __shared__ float lnmu[8], lnrs[8];
    {
        int h = t >> 6, dd = t & 63;
        float sq = 0, sk = 0;
        for (int b = 0; b < 8; ++b) {
            sq += csq[(h * 8 + b) * 64 + dd];
            sk += csk[(h * 8 + b) * 64 + dd];
        }
        cat[h][dd]      = sq * (1.f / 8192.f);
        cat[h][64 + dd] = sk * (1.f / 8192.f);
    }
    __syncthreads();
    {
        int h = t >> 6, j = t & 63;
        float a = b1[j];
        for (int i = 0; i < 128; ++i) a = fmaf(cat[h][i], W1[i * 64 + j], a);
        z1[h][j] = a;
    }
    __syncthreads();
    if (t < 8) {
        float m = 0;
        for (int j = 0; j < 64; ++j) m += z1[t][j];
        m *= (1.f / 64.f);
        float v2 = 0;
        for (int j = 0; j < 64; ++j) { float d = z1[t][j] - m; v2 += d * d; }
        v2 *= (1.f / 64.f);
        lnmu[t] = m; lnrs[t] = rsqrtf(v2 + 1e-5f);
    }
    __syncthreads();
    {
        int h = t >> 6, j = t & 63;
        float z = (z1[h][j] - lnmu[h]) * lnrs[h] * lg[j] + lb[j];
        zr[h][j] = fmaxf(z, 0.f);
    }
    __syncthreads();
    if (t < 256) {
        int h = t >> 5, j2 = t & 31;
        float a = b2[j2];
        for (int j = 0; j < 64; ++j) a = fmaf(zr[h][j], W2[j * 32 + j2], a);
        z2[h][j2] = fmaxf(a, 0.f);
    }
    __syncthreads();
    if (t < 24) {
        int h = t / 3, c = t % 3;
        float a = b3[c];
        for (int j2 = 0; j2 < 32; ++j2) a = fmaf(z2[h][j2], W3[j2 * 3 + c], a);
        z3[h][c] = a;
    }
    __syncthreads();
    if (t < 8) {
        int h = t;
        float wt = fminf(fmaxf(wtemp[0], 0.1f), 10.f);
        float a = z3[h][0], b = z3[h][1], c = z3[h][2];
        float mx = fmaxf(a, fmaxf(b, c));
        float ea = expf(a - mx), eb = expf(b - mx), ec = expf(c - mx);
        float s = ea + eb + ec;
        float p0 = ea / s, p1 = eb / s, p2 = ec / s;
        float q0 = p0 / wt, q1 = p1 / wt, q2 = p2 / wt;
        mx = fmaxf(q0, fmaxf(q1, q2));
        ea = expf(q0 - mx); eb = expf(q1 - mx); ec = expf(q2 - mx);
        s = ea + eb + ec;
        wbuf[h * 3 + 0] = (ea / s) * 0.7f + 0.1f;
        wbuf[h * 3 + 1] = (eb / s) * 0.7f + 0.1f;
        wbuf[h * 3 + 2] = (ec / s) * 0.7f + 0.1f;
    }
}

// ---------------- K4: pass 1 — single RN-bf16 MFMA (stats only), 4-way key split ----------------
__global__ __launch_bounds__(256) void k_pass1(
    const unsigned short* __restrict__ Fqhi, const unsigned short* __restrict__ Fkhi,
    const float* __restrict__ qinvA, const float* __restrict__ mqA, const float* __restrict__ gA,
    const float* __restrict__ kinvA, const float* __restrict__ ksA,
    float* __restrict__ rowA, float* __restrict__ rowM,
    double* __restrict__ accum)
{
    int bx = blockIdx.x;
    int loc = bx >> 3;
    int hb = (bx & 7) * 8 + (loc >> 6);
    int rem = loc & 63;
    int n0 = (rem >> 2) * 64;
    int mtc = rem & 3;
    int h = hb >> 3;
    __shared__ unsigned short Khi[64][72];
    __shared__ float ki1s[64], ksls[64];
    __shared__ double wsum[4][4];
    int t = threadIdx.x;
    int w = t >> 6, lane = t & 63, l15 = lane & 15, kb = lane >> 4;
    int srow = t >> 2, seg = t & 3;
    const float SC = (float)((0.001 / 1024.0) / (8.0 + 1e-6));

    fragu qh[2];
    {
        long long qbase = ((long long)hb * N_ + n0 + w * 16 + l15) * D_;
#pragma unroll
        for (int k2 = 0; k2 < 2; ++k2)
            qh[k2].q = *(const uint4*)(Fqhi + qbase + k2 * 32 + kb * 8);
    }
    float qi1_r[4], qm_r[4], qgs_r[4];
#pragma unroll
    for (int r = 0; r < 4; ++r) {
        int rowg = hb * N_ + n0 + w * 16 + kb * 4 + r;
        qi1_r[r] = qinvA[rowg];
        qm_r[r]  = mqA[rowg];
        qgs_r[r] = gA[rowg] * SC;
    }
    // sacc: 0=SumA 1=SumA2 2=SumB2 3=SumAB 4=Sum min(A,0.01)
    float sacc[5][4] = {};

    for (int mt = mtc * 4; mt < mtc * 4 + 4; ++mt) {
        {
            long long kro = ((long long)hb * N_ + mt * 64 + srow) * D_ + seg * 16;
            uint4 h0 = *(const uint4*)(Fkhi + kro), h1 = *(const uint4*)(Fkhi + kro + 8);
            *(uint4*)&Khi[srow][seg * 16]     = h0;
            *(uint4*)&Khi[srow][seg * 16 + 8] = h1;
            if (t < 64) {
                ki1s[t] = kinvA[hb * N_ + mt * 64 + t];
                ksls[t] = ksA[hb * N_ + mt * 64 + t];
            }
        }
        __syncthreads();
#pragma unroll
        for (int nt = 0; nt < 4; ++nt) {
            f4v acc = {0.f, 0.f, 0.f, 0.f};
            s8v kh0 = *(const s8v*)&Khi[nt * 16 + l15][kb * 8];
            s8v kh1 = *(const s8v*)&Khi[nt * 16 + l15][32 + kb * 8];
            acc = BMFMA(qh[0].v, kh0, acc);
            acc = BMFMA(qh[1].v, kh1, acc);
            int key = nt * 16 + l15;
            float k1 = ki1s[key];
            float ksvSC = ksls[key] * SC;
            float e_r[4];
#pragma unroll
            for (int r = 0; r < 4; ++r) e_r[r] = fmaf(qm_r[r], ksvSC, qgs_r[r]);
#pragma unroll
            for (int r = 0; r < 4; ++r) {
                float dv = acc[r];
                float A  = dv * qi1_r[r] * k1;
                float Bv = fmaf(dv, SC, -e_r[r]);
                sacc[0][r] += A;
                sacc[1][r] = fmaf(A, A, sacc[1][r]);
                sacc[2][r] = fmaf(Bv, Bv, sacc[2][r]);
                sacc[3][r] = fmaf(A, Bv, sacc[3][r]);
                sacc[4][r] += fminf(A, 0.01f);
            }
        }
        __syncthreads();
    }
    {
        const int map[4] = {0, 3, 4, 6};
#pragma unroll
        for (int qq = 0; qq < 4; ++qq) {
            float s = sacc[qq][0] + sacc[qq][1] + sacc[qq][2] + sacc[qq][3];
            double d = wred_sum_d((double)s);
            if (lane == 0) wsum[qq][w] = d;
        }
        __syncthreads();
        if (t < 4) {
            double tot = wsum[t][0] + wsum[t][1] + wsum[t][2] + wsum[t][3];
            atomicAdd(&accum[h * 9 + map[t]], tot);
        }
    }
    float vA[4], vM[4];
#pragma unroll
    for (int r = 0; r < 4; ++r) {
        float a = sacc[0][r], m = sacc[4][r];
#pragma unroll
        for (int msk = 8; msk >= 1; msk >>= 1) {
            a += __shfl_xor(a, msk, 64);
            m += __shfl_xor(m, msk, 64);
        }
        vA[r] = a; vM[r] = m;
    }
    if (l15 == 0) {
#pragma unroll
        for (int r = 0; r < 4; ++r) {
            int rowg = hb * N_ + n0 + w * 16 + kb * 4 + r;
            atomicAdd(&rowA[rowg], vA[r]);
            // Σ max(0.01-A,0) over this block's 256 keys = 0.01*256 - Σ min(A,0.01)
            atomicAdd(&rowM[rowg], 2.56f - vM[r]);
        }
    }
}

// ---------------- K4b: row-sum finalization + varC + (last block) global finalize ----------------
__global__ __launch_bounds__(256) void k_rowfin(
    const float* __restrict__ rowA, const float* __restrict__ rowM,
    float* __restrict__ varC, double* __restrict__ accum,
    const float* __restrict__ wbuf, float* __restrict__ scl,
    unsigned* __restrict__ ticket)
{
    int hb = blockIdx.x;
    int h = hb >> 3;
    int t = threadIdx.x;
    int w = t >> 6, lane = t & 63;
    __shared__ double wsum[3][4];
    double c2 = 0, c5 = 0, c7 = 0;
    for (int i = t; i < N_; i += 256) {
        int idx = hb * N_ + i;
        float rm = rowM[idx];
        float C = rm * (1.f / 1024.f);
        varC[idx] = C;
        c2 += (double)rm;
        c5 += (double)rm * (double)C;
        c7 += (double)C * (double)rowA[idx];
    }
    c2 = wred_sum_d(c2); c5 = wred_sum_d(c5); c7 = wred_sum_d(c7);
    if (lane == 0) { wsum[0][w] = c2; wsum[1][w] = c5; wsum[2][w] = c7; }
    __syncthreads();
    if (t < 3) {
        const int map[3] = {2, 5, 7};
        double tot = wsum[t][0] + wsum[t][1] + wsum[t][2] + wsum[t][3];
        atomicAdd(&accum[h * 9 + map[t]], tot);
    }
    // ---- last block to finish runs the (tiny) global finalize ----
    __syncthreads();   // drains the t<3 atomics (waitcnt before barrier)
    __shared__ unsigned lastv;
    if (t == 0) {
        __threadfence();
        lastv = atomicAdd(ticket, 1u);
    }
    __syncthreads();
    if (lastv != 63 || t != 0) return;

    double av[8][9];
#pragma unroll
    for (int hh = 0; hh < 8; ++hh)
#pragma unroll
        for (int j = 0; j < 9; ++j)
            av[hh][j] = __hip_atomic_load(&accum[hh * 9 + j], __ATOMIC_RELAXED, __HIP_MEMORY_SCOPE_AGENT);
    const double T = 67108864.0;
    double GA = 0, GB = 0, GC = 0, GAA = 0, GBB = 0, GCC = 0;
#pragma unroll
    for (int hh = 0; hh < 8; ++hh) {
        GA += av[hh][0]; GB += av[hh][1]; GC += av[hh][2];
        GAA += av[hh][3]; GBB += av[hh][4]; GCC += av[hh][5];
    }
    double cos_n = sqrt(fmax((GAA - GA * GA / T) / (T - 1.0), 0.0)) + 1e-6;
    double cov_n = sqrt(fmax((GBB - GB * GB / T) / (T - 1.0), 0.0)) + 1e-6;
    double var_n = sqrt(fmax((GCC - GC * GC / T) / (T - 1.0), 0.0)) + 1e-6;
    double sd = 0, sd2 = 0;
    double al[8], be[8], ga[8];
#pragma unroll
    for (int hh = 0; hh < 8; ++hh) {
        al[hh] = (double)wbuf[hh * 3 + 0] / cos_n;
        be[hh] = (double)wbuf[hh * 3 + 1] * 0.3 / cov_n;
        ga[hh] = (double)wbuf[hh * 3 + 2] * 0.3 / var_n;
        sd  += al[hh] * av[hh][0] + be[hh] * av[hh][1] + ga[hh] * av[hh][2];
        sd2 += al[hh] * al[hh] * av[hh][3] + be[hh] * be[hh] * av[hh][4] + ga[hh] * ga[hh] * av[hh][5]
             + 2.0 * al[hh] * be[hh] * av[hh][6] + 2.0 * al[hh] * ga[hh] * av[hh][7]
             + 2.0 * be[hh] * ga[hh] * av[hh][8];
    }
    double vard = fmax((sd2 - sd * sd / T) / (T - 1.0), 0.0);
    double temp = 0.5 + sqrt(vard);
    temp = fmin(fmax(temp, 0.3), 3.0);
#pragma unroll
    for (int hh = 0; hh < 8; ++hh) {
        scl[hh * 3 + 0] = (float)(al[hh] / temp);
        scl[hh * 3 + 1] = (float)(be[hh] / temp);
        scl[hh * 3 + 2] = (float)(ga[hh] / temp);
    }
}

// ---------------- K5: pass 2 — 8 waves x 32 q-rows/wave, 256 rows/block ----------------
__global__ __launch_bounds__(512, 2) void k_pass2(
    const unsigned short* __restrict__ Fqhi, const unsigned short* __restrict__ Fqlo,
    const unsigned short* __restrict__ Fkhi, const unsigned short* __restrict__ Fklo,
    const unsigned short* __restrict__ Fvthi, const unsigned short* __restrict__ Fvtlo,
    const float* __restrict__ qinvA, const float* __restrict__ mqA, const float* __restrict__ gA,
    const float* __restrict__ kinvA, const float* __restrict__ ksA,
    const float* __restrict__ varC, const float* __restrict__ scl,
    unsigned short* __restrict__ attn_hi, unsigned short* __restrict__ attn_lo)
{
    int bx = blockIdx.x;
    int g = bx >> 3;
    int hb = (bx & 7) * 8 + (g >> 2);   // XCD-local hb
    int n0 = (g & 3) * 256;             // 256 q-rows per block
    int h = hb >> 3, b = hb & 7;
    __shared__ unsigned short Khi[2][64][72];
    __shared__ unsigned short Klo[2][64][72];
    __shared__ unsigned short Vh[2][64][72];
    __shared__ unsigned short Vl[2][64][72];
    __shared__ float ki1s[2][64], ksls[2][64];
    int t = threadIdx.x;
    int w = t >> 6, lane = t & 63, l15 = lane & 15, kb = lane >> 4;
    int srow = t >> 3, sc = (t & 7) * 8;
    const float SC = (float)((0.001 / 1024.0) / (8.0 + 1e-6));
    const float L2E = 1.44269504f;      // log2(e): work in exp2 domain
    float sAh = scl[h*3+0] * L2E, sBh = scl[h*3+1] * L2E, sCh = scl[h*3+2] * L2E;
    float SCb = SC * sBh;

    fragu qh0[2], ql0[2], qh1[2], ql1[2];
    int rowq0 = hb * N_ + n0 + w * 32 + l15;
    int rowq1 = rowq0 + 16;
    {
        long long qb0 = (long long)rowq0 * D_;
        long long qb1 = (long long)rowq1 * D_;
#pragma unroll
        for (int k2 = 0; k2 < 2; ++k2) {
            qh0[k2].q = *(const uint4*)(Fqhi + qb0 + k2 * 32 + kb * 8);
            ql0[k2].q = *(const uint4*)(Fqlo + qb0 + k2 * 32 + kb * 8);
            qh1[k2].q = *(const uint4*)(Fqhi + qb1 + k2 * 32 + kb * 8);
            ql1[k2].q = *(const uint4*)(Fqlo + qb1 + k2 * 32 + kb * 8);
        }
    }
    float qiA0 = qinvA[rowq0] * sAh;
    float qiA1 = qinvA[rowq1] * sAh;
    float nqmS0 = -mqA[rowq0] * SCb;
    float nqmS1 = -mqA[rowq1] * SCb;
    float cb0 = fmaf(sCh, varC[rowq0], -(gA[rowq0] * SC) * sBh);
    float cb1 = fmaf(sCh, varC[rowq1], -(gA[rowq1] * SC) * sBh);

    float Mr0 = -1e30f, Lr0 = 0.f, Mr1 = -1e30f, Lr1 = 0.f;
    f4v oacc0[4], oacc1[4];
#pragma unroll
    for (int dt = 0; dt < 4; ++dt) {
        oacc0[dt] = (f4v){0.f, 0.f, 0.f, 0.f};
        oacc1[dt] = (f4v){0.f, 0.f, 0.f, 0.f};
    }
    int idxr[4];
#pragma unroll
    for (int r = 0; r < 4; ++r) idxr[r] = (kb * 20 + r) * 4;

    uint4 rkh, rkl, rvh, rvl;
    float rki, rks;
#define P2_LOAD(MT) { \
    long long kro = ((long long)hb * N_ + (MT) * 64 + srow) * D_ + sc; \
    rkh = *(const uint4*)(Fkhi + kro); rkl = *(const uint4*)(Fklo + kro); \
    long long vro = ((long long)hb * D_ + srow) * N_ + (MT) * 64 + sc; \
    rvh = *(const uint4*)(Fvthi + vro); rvl = *(const uint4*)(Fvtlo + vro); \
    if (t < 64) { rki = kinvA[hb * N_ + (MT) * 64 + t]; rks = ksA[hb * N_ + (MT) * 64 + t]; } }

    P2_LOAD(0)
    for (int mt = 0; mt < 16; ++mt) {
        int buf = mt & 1;
        *(uint4*)&Khi[buf][srow][sc] = rkh;
        *(uint4*)&Klo[buf][srow][sc] = rkl;
        *(uint4*)&Vh[buf][srow][sc]  = rvh;
        *(uint4*)&Vl[buf][srow][sc]  = rvl;
        if (t < 64) { ki1s[buf][t] = rki; ksls[buf][t] = rks; }
        __syncthreads();
        if (mt < 15) { P2_LOAD(mt + 1) }
        float p0[4][4], p1[4][4];
#pragma unroll
        for (int nt = 0; nt < 4; ++nt) {
            f4v a0 = {0.f, 0.f, 0.f, 0.f};
            f4v a1 = {0.f, 0.f, 0.f, 0.f};
            __builtin_amdgcn_s_setprio(1);
#pragma unroll
            for (int k2 = 0; k2 < 2; ++k2) {
                s8v kh = *(const s8v*)&Khi[buf][nt * 16 + l15][k2 * 32 + kb * 8];
                s8v kl = *(const s8v*)&Klo[buf][nt * 16 + l15][k2 * 32 + kb * 8];
                a0 = BMFMA(kh, qh0[k2].v, a0);
                a0 = BMFMA(kh, ql0[k2].v, a0);
                a0 = BMFMA(kl, qh0[k2].v, a0);
                a1 = BMFMA(kh, qh1[k2].v, a1);
                a1 = BMFMA(kh, ql1[k2].v, a1);
                a1 = BMFMA(kl, qh1[k2].v, a1);
            }
            __builtin_amdgcn_s_setprio(0);
            float4 k1v = *(const float4*)&ki1s[buf][nt * 16 + kb * 4];
            float4 ksv = *(const float4*)&ksls[buf][nt * 16 + kb * 4];
            float k1a[4] = {k1v.x, k1v.y, k1v.z, k1v.w};
            float ksa[4] = {ksv.x, ksv.y, ksv.z, ksv.w};
#pragma unroll
            for (int r = 0; r < 4; ++r) {
                p0[nt][r] = fmaf(a0[r], fmaf(qiA0, k1a[r], SCb), fmaf(nqmS0, ksa[r], cb0));
                p1[nt][r] = fmaf(a1[r], fmaf(qiA1, k1a[r], SCb), fmaf(nqmS1, ksa[r], cb1));
            }
        }
        fragu pah0[2], pal0[2], pah1[2], pal1[2];
        // ---- softmax row-group 0 ----
        {
            float tmax = fmaxf(fmaxf(fmaxf(p0[0][0], p0[0][1]), fmaxf(p0[0][2], p0[0][3])),
                               fmaxf(fmaxf(p0[1][0], p0[1][1]), fmaxf(p0[1][2], p0[1][3])));
            tmax = fmaxf(tmax, fmaxf(fmaxf(fmaxf(p0[2][0], p0[2][1]), fmaxf(p0[2][2], p0[2][3])),
                                     fmaxf(fmaxf(p0[3][0], p0[3][1]), fmaxf(p0[3][2], p0[3][3]))));
            tmax = kbmax4(tmax);
            if (__any(tmax - Mr0 > 11.5415605f)) {
                float nM = fmaxf(Mr0, tmax);
                float scf = fexp2(Mr0 - nM);
                Mr0 = nM;
                Lr0 *= scf;
                float s0 = __int_as_float(__builtin_amdgcn_ds_bpermute(idxr[0], __float_as_int(scf)));
                float s1 = __int_as_float(__builtin_amdgcn_ds_bpermute(idxr[1], __float_as_int(scf)));
                float s2 = __int_as_float(__builtin_amdgcn_ds_bpermute(idxr[2], __float_as_int(scf)));
                float s3 = __int_as_float(__builtin_amdgcn_ds_bpermute(idxr[3], __float_as_int(scf)));
#pragma unroll
                for (int dt = 0; dt < 4; ++dt) {
                    oacc0[dt][0] *= s0; oacc0[dt][1] *= s1;
                    oacc0[dt][2] *= s2; oacc0[dt][3] *= s3;
                }
            }
            float ps = 0.f;
#pragma unroll
            for (int nt = 0; nt < 4; ++nt)
#pragma unroll
                for (int r = 0; r < 4; ++r) {
                    float e = fexp2(p0[nt][r] - Mr0);
                    p0[nt][r] = e;
                    ps += e;
                }
            ps = kbsum4(ps);
            Lr0 += ps;
#pragma unroll
            for (int k2 = 0; k2 < 2; ++k2) {
#pragma unroll
                for (int j = 0; j < 4; ++j) {
                    float x = p0[2 * k2 + (j >> 1)][(j & 1) * 2];
                    float y = p0[2 * k2 + (j >> 1)][(j & 1) * 2 + 1];
                    unsigned hw2 = cvtpk(x, y);
                    pah0[k2].w[j] = hw2;
                    float lx = x - __uint_as_float(hw2 << 16);
                    float ly = y - __uint_as_float(hw2 & 0xFFFF0000u);
                    pal0[k2].w[j] = cvtpk(lx, ly);
                }
            }
        }
        // ---- softmax row-group 1 ----
        {
            float tmax = fmaxf(fmaxf(fmaxf(p1[0][0], p1[0][1]), fmaxf(p1[0][2], p1[0][3])),
                               fmaxf(fmaxf(p1[1][0], p1[1][1]), fmaxf(p1[1][2], p1[1][3])));
            tmax = fmaxf(tmax, fmaxf(fmaxf(fmaxf(p1[2][0], p1[2][1]), fmaxf(p1[2][2], p1[2][3])),
                                     fmaxf(fmaxf(p1[3][0], p1[3][1]), fmaxf(p1[3][2], p1[3][3]))));
            tmax = kbmax4(tmax);
            if (__any(tmax - Mr1 > 11.5415605f)) {
                float nM = fmaxf(Mr1, tmax);
                float scf = fexp2(Mr1 - nM);
                Mr1 = nM;
                Lr1 *= scf;
                float s0 = __int_as_float(__builtin_amdgcn_ds_bpermute(idxr[0], __float_as_int(scf)));
                float s1 = __int_as_float(__builtin_amdgcn_ds_bpermute(idxr[1], __float_as_int(scf)));
                float s2 = __int_as_float(__builtin_amdgcn_ds_bpermute(idxr[2], __float_as_int(scf)));
                float s3 = __int_as_float(__builtin_amdgcn_ds_bpermute(idxr[3], __float_as_int(scf)));
#pragma unroll
                for (int dt = 0; dt < 4; ++dt) {
                    oacc1[dt][0] *= s0; oacc1[dt][1] *= s1;
                    oacc1[dt][2] *= s2; oacc1[dt][3] *= s3;
                }
            }
            float ps = 0.f;
#pragma unroll
            for (int nt = 0; nt < 4; ++nt)
#pragma unroll
                for (int r = 0; r < 4; ++r) {
                    float e = fexp2(p1[nt][r] - Mr1);
                    p1[nt][r] = e;
                    ps += e;
                }
            ps = kbsum4(ps);
            Lr1 += ps;
#pragma unroll
            for (int k2 = 0; k2 < 2; ++k2) {
#pragma unroll
                for (int j = 0; j < 4; ++j) {
                    float x = p1[2 * k2 + (j >> 1)][(j & 1) * 2];
                    float y = p1[2 * k2 + (j >> 1)][(j & 1) * 2 + 1];
                    unsigned hw2 = cvtpk(x, y);
                    pah1[k2].w[j] = hw2;
                    float lx = x - __uint_as_float(hw2 << 16);
                    float ly = y - __uint_as_float(hw2 & 0xFFFF0000u);
                    pal1[k2].w[j] = cvtpk(lx, ly);
                }
            }
        }
        // ---- PV: shared V fragment reads feed both row-groups ----
        __builtin_amdgcn_s_setprio(1);
#pragma unroll
        for (int dt = 0; dt < 4; ++dt) {
#pragma unroll
            for (int k2 = 0; k2 < 2; ++k2) {
                s8v vh2 = *(const s8v*)&Vh[buf][dt * 16 + l15][k2 * 32 + kb * 8];
                s8v vl2 = *(const s8v*)&Vl[buf][dt * 16 + l15][k2 * 32 + kb * 8];
                oacc0[dt] = BMFMA(pah0[k2].v, vh2, oacc0[dt]);
                oacc0[dt] = BMFMA(pah0[k2].v, vl2, oacc0[dt]);
                oacc0[dt] = BMFMA(pal0[k2].v, vh2, oacc0[dt]);
                oacc1[dt] = BMFMA(pah1[k2].v, vh2, oacc1[dt]);
                oacc1[dt] = BMFMA(pah1[k2].v, vl2, oacc1[dt]);
                oacc1[dt] = BMFMA(pal1[k2].v, vh2, oacc1[dt]);
            }
        }
        __builtin_amdgcn_s_setprio(0);
    }
#undef P2_LOAD
    // ---- epilogue rg0 ----
    {
        float i0 = 1.f / __int_as_float(__builtin_amdgcn_ds_bpermute(idxr[0], __float_as_int(Lr0)));
        float i1 = 1.f / __int_as_float(__builtin_amdgcn_ds_bpermute(idxr[1], __float_as_int(Lr0)));
        float i2 = 1.f / __int_as_float(__builtin_amdgcn_ds_bpermute(idxr[2], __float_as_int(Lr0)));
        float i3 = 1.f / __int_as_float(__builtin_amdgcn_ds_bpermute(idxr[3], __float_as_int(Lr0)));
        float inv_r[4] = {i0, i1, i2, i3};
#pragma unroll
        for (int dt = 0; dt < 4; ++dt)
#pragma unroll
            for (int r = 0; r < 4; ++r) {
                float o = oacc0[dt][r] * inv_r[r];
                unsigned short hi, lo;
                bsplit(o, hi, lo);
                long long idx = ((long long)(b * N_ + n0 + w * 32 + kb * 4 + r)) * DIMM
                              + h * 64 + dt * 16 + l15;
                attn_hi[idx] = hi;
                attn_lo[idx] = lo;
            }
    }
    // ---- epilogue rg1 ----
    {
        float i0 = 1.f / __int_as_float(__builtin_amdgcn_ds_bpermute(idxr[0], __float_as_int(Lr1)));
        float i1 = 1.f / __int_as_float(__builtin_amdgcn_ds_bpermute(idxr[1], __float_as_int(Lr1)));
        float i2 = 1.f / __int_as_float(__builtin_amdgcn_ds_bpermute(idxr[2], __float_as_int(Lr1)));
        float i3 = 1.f / __int_as_float(__builtin_amdgcn_ds_bpermute(idxr[3], __float_as_int(Lr1)));
        float inv_r[4] = {i0, i1, i2, i3};
#pragma unroll
        for (int dt = 0; dt < 4; ++dt)
#pragma unroll
            for (int r = 0; r < 4; ++r) {
                float o = oacc1[dt][r] * inv_r[r];
                unsigned short hi, lo;
                bsplit(o, hi, lo);
                long long idx = ((long long)(b * N_ + n0 + w * 32 + 16 + kb * 4 + r)) * DIMM
                              + h * 64 + dt * 16 + l15;
                attn_hi[idx] = hi;
                attn_lo[idx] = lo;
            }
    }
}

// ---------------- K6: output GEMM, 128x128 blocks — 64x64 per-wave tiles ----------------
__global__ __launch_bounds__(256) void k_gemm_out(
    const unsigned short* __restrict__ Ahi, const unsigned short* __restrict__ Alo,
    const unsigned short* __restrict__ Wothi, const unsigned short* __restrict__ Wotlo,
    const float* __restrict__ bias, float* __restrict__ out)
{
    int row0 = blockIdx.x * 128, j0 = blockIdx.y * 128;
    __shared__ unsigned short Ah[128][32], Al[128][32];
    __shared__ unsigned short Bh[128][32], Bl[128][32];
    int t = threadIdx.x;
    int w = t >> 6, lane = t & 63, l15 = lane & 15, kb = lane >> 4;
    int srow = t >> 1, sseg = t & 1;
    int sw = (srow >> 1) & 3;
    int c0 = ((2 * sseg + 0) ^ sw) * 8;
    int c1 = ((2 * sseg + 1) ^ sw) * 8;
    int rs = (l15 >> 1) & 3;
    int rb = (kb ^ rs) * 8;
    int rhalf = (w & 1) * 64;
    int chalf = (w >> 1) * 64;
    f4v acc[4][4];
#pragma unroll
    for (int rt = 0; rt < 4; ++rt)
#pragma unroll
        for (int dt = 0; dt < 4; ++dt) acc[rt][dt] = (f4v){0.f, 0.f, 0.f, 0.f};
    uint4 a0, a1, al0, al1, b0, b1, bl0, bl1;
#define GOUT_LOAD(KC) { \
    int kO = (KC) * 32 + sseg * 16; \
    const unsigned short* ap  = Ahi + (long long)(row0 + srow) * DIMM + kO; \
    const unsigned short* alp = Alo + (long long)(row0 + srow) * DIMM + kO; \
    a0 = *(const uint4*)ap;  a1 = *(const uint4*)(ap + 8); \
    al0 = *(const uint4*)alp; al1 = *(const uint4*)(alp + 8); \
    const unsigned short* bp  = Wothi + (long long)(j0 + srow) * DIMM + kO; \
    const unsigned short* blp = Wotlo + (long long)(j0 + srow) * DIMM + kO; \
    b0 = *(const uint4*)bp;  b1 = *(const uint4*)(bp + 8); \
    bl0 = *(const uint4*)blp; bl1 = *(const uint4*)(blp + 8); }

    GOUT_LOAD(0)
    for (int kc = 0; kc < 16; ++kc) {
        *(uint4*)&Ah[srow][c0] = a0;
        *(uint4*)&Ah[srow][c1] = a1;
        *(uint4*)&Al[srow][c0] = al0;
        *(uint4*)&Al[srow][c1] = al1;
        *(uint4*)&Bh[srow][c0] = b0;
        *(uint4*)&Bh[srow][c1] = b1;
        *(uint4*)&Bl[srow][c0] = bl0;
        *(uint4*)&Bl[srow][c1] = bl1;
        __syncthreads();
        if (kc < 15) { GOUT_LOAD(kc + 1) }
        fragu ah[4], al2[4];
#pragma unroll
        for (int rt = 0; rt < 4; ++rt) {
            ah[rt].v  = *(const s8v*)&Ah[rhalf + rt * 16 + l15][rb];
            al2[rt].v = *(const s8v*)&Al[rhalf + rt * 16 + l15][rb];
        }
#pragma unroll
        for (int dt = 0; dt < 4; ++dt) {
            s8v bh = *(const s8v*)&Bh[chalf + dt * 16 + l15][rb];
            s8v bl = *(const s8v*)&Bl[chalf + dt * 16 + l15][rb];
#pragma unroll
            for (int rt = 0; rt < 4; ++rt) {
                acc[rt][dt] = BMFMA(ah[rt].v, bh, acc[rt][dt]);
                acc[rt][dt] = BMFMA(ah[rt].v, bl, acc[rt][dt]);
                acc[rt][dt] = BMFMA(al2[rt].v, bh, acc[rt][dt]);
            }
        }
        __syncthreads();
    }
#undef GOUT_LOAD
#pragma unroll
    for (int dt = 0; dt < 4; ++dt) {
        float bv = bias[j0 + chalf + dt * 16 + l15];
#pragma unroll
        for (int rt = 0; rt < 4; ++rt)
#pragma unroll
            for (int r = 0; r < 4; ++r)
                out[(long long)(row0 + rhalf + rt * 16 + kb * 4 + r) * DIMM
                    + j0 + chalf + dt * 16 + l15] = acc[rt][dt][r] + bv;
    }
}

extern "C" void kernel_launch(void* const* d_in, const int* in_sizes, int n_in,
                              void* d_out, int out_size, void* d_ws, size_t ws_size,
                              hipStream_t stream) {
    (void)in_sizes; (void)n_in; (void)out_size; (void)ws_size;
    const float* q      = (const float*)d_in[0];
    const float* k      = (const float*)d_in[1];
    const float* v      = (const float*)d_in[2];
    const float* ln_g   = (const float*)d_in[3];
    const float* ln_b   = (const float*)d_in[4];
    const float* W_in   = (const float*)d_in[5];
    const float* wp_W1  = (const float*)d_in[6];
    const float* wp_b1  = (const float*)d_in[7];
    const float* wp_lng = (const float*)d_in[8];
    const float* wp_lnb = (const float*)d_in[9];
    const float* wp_W2  = (const float*)d_in[10];
    const float* wp_b2  = (const float*)d_in[11];
    const float* wp_W3  = (const float*)d_in[12];
    const float* wp_b3  = (const float*)d_in[13];
    const float* wtemp  = (const float*)d_in[14];
    const float* W_out  = (const float*)d_in[15];
    const float* b_out  = (const float*)d_in[16];
    float* out = (float*)d_out;

    char* w = (char*)d_ws;
    unsigned short* attn_hi = (unsigned short*)(w + 0);
    unsigned short* attn_lo = (unsigned short*)(w + 8388608);
    unsigned short* Fqhi  = (unsigned short*)(w + 16777216);
    unsigned short* Fqlo  = (unsigned short*)(w + 25165824);
    unsigned short* Fkhi  = (unsigned short*)(w + 33554432);
    unsigned short* Fklo  = (unsigned short*)(w + 41943040);
    unsigned short* Fvthi = (unsigned short*)(w + 50331648);
    unsigned short* Fvtlo = (unsigned short*)(w + 58720256);
    unsigned short* Wthi  = (unsigned short*)(w + 67108864);
    unsigned short* Wtlo  = (unsigned short*)(w + 67633152);
    unsigned short* Wothi = (unsigned short*)(w + 68157440);
    unsigned short* Wotlo = (unsigned short*)(w + 68681728);
    float* muv  = (float*)(w + 69206016);
    float* rsd  = (float*)(w + 69304320);
    float* qinv = (float*)(w + 69402624);
    float* mq   = (float*)(w + 69664768);
    float* gv   = (float*)(w + 69926912);
    float* kinv = (float*)(w + 70189056);
    float* ks   = (float*)(w + 70451200);
    float* vc   = (float*)(w + 70713344);
    float* rowA = (float*)(w + 70975488);
    float* rowB = (float*)(w + 71237632);   // (unused, kept for layout stability)
    float* rowM = (float*)(w + 71499776);
    float* csq  = (float*)(w + 71761920);
    float* csk  = (float*)(w + 71778304);
    double* acc = (double*)(w + 71794688);
    float* wb   = (float*)(w + 71796736);
    float* scl  = (float*)(w + 71796864);
    unsigned* ticket = (unsigned*)(w + 71794688 + 768);  // inside zeroed acc slab
    (void)rowB;

    // zero rowA/rowB/rowM (3 x 256KB) + csq/csk (2 x 16KB) + accum/ticket slab
    hipMemsetAsync(rowA, 0, 3 * 262144 + 2 * 16384 + 2048, stream);

    k_prep<<<6272, 256, 0, stream>>>(q, k, v, muv, rsd, W_in, W_out, Wthi, Wtlo, Wothi, Wotlo);
    k_gemm_in<<<dim3(64, 4, 3), 256, 0, stream>>>(q, k, v, muv, rsd, ln_g, ln_b,
                                                  Wthi, Wtlo, Fqhi, Fqlo, Fkhi, Fklo, Fvthi, Fvtlo,
                                                  qinv, mq, kinv, ks, csq, csk);
    k_gvec_mlp<<<129, 512, 0, stream>>>(Fqhi, Fqlo, csk, mq, gv, csq,
                                        wp_W1, wp_b1, wp_lng, wp_lnb, wp_W2, wp_b2, wp_W3, wp_b3,
                                        wtemp, wb);
    k_pass1<<<4096, 256, 0, stream>>>(Fqhi, Fkhi, qinv, mq, gv, kinv, ks, rowA, rowM, acc);
    k_rowfin<<<64, 256, 0, stream>>>(rowA, rowM, vc, acc, wb, scl, ticket);
    k_pass2<<<256, 512, 0, stream>>>(Fqhi, Fqlo, Fkhi, Fklo, Fvthi, Fvtlo,
                                     qinv, mq, gv, kinv, ks, vc, scl, attn_hi, attn_lo);
    k_gemm_out<<<dim3(64, 4), 256, 0, stream>>>(attn_hi, attn_lo, Wothi, Wotlo, b_out, out);
}